// Round 9
// baseline (386.971 us; speedup 1.0000x reference)
//
#include <hip/hip_runtime.h>
#include <cstdint>
#include <cstddef>

// ---------------------------------------------------------------------------
// TransformConvCrossAttention: B=4, SQ=SK=2048, D=1024, Kconv=3
// fp16 compute, fp32 MFMA accumulation; fp32 in/out (runtime-verified).
// R19 (= R18 resubmit after infra-signature failure; dead code removed):
//   k_prep fp32: 8 dense 16B quanta/thread -> 8B dense stores, loads fenced
//                before converts (fixes half-utilized-line request-rate bound
//                seen in R16/R17: pinned 1.84 TB/s).
//   k_softmax:   block per MASK row, 4 batch rows (one per wave) share the
//                mask read -> mask traffic / 4.
//   GEMM + convs kernels byte-identical to R17.
// ---------------------------------------------------------------------------

#define GLOBAL_AS __attribute__((address_space(1)))
#define LDS_AS    __attribute__((address_space(3)))

typedef _Float16 h8 __attribute__((ext_vector_type(8)));
typedef _Float16 h4 __attribute__((ext_vector_type(4)));
typedef float    f4_t __attribute__((ext_vector_type(4)));
typedef unsigned short us8 __attribute__((ext_vector_type(8)));
typedef unsigned int u32x4 __attribute__((ext_vector_type(4)));

__device__ __forceinline__ float bf2f(unsigned short u) {
    union { unsigned int i; float f; } x; x.i = ((unsigned int)u) << 16; return x.f;
}
__device__ __forceinline__ float rd(const void* p, long i, int isBf) {
    return isBf ? bf2f(((const unsigned short*)p)[i]) : ((const float*)p)[i];
}

// ---------------------------------------------------------------------------
// Probes: blocks 0..15 = dtype sniff per tensor; block 16 = mask width.
struct Probe16 { const unsigned short* p[16]; int n[16]; };

__global__ void k_probes(Probe16 a, const unsigned int* __restrict__ mask,
                         int* __restrict__ flags) {
    if (blockIdx.x < 16) {
        __shared__ int cnt;
        if (threadIdx.x == 0) cnt = 0;
        __syncthreads();
        const unsigned short* s = a.p[blockIdx.x];
        const int n = a.n[blockIdx.x];
        int bad = 0;
        for (int i = threadIdx.x; i < n; i += 256) {
            int e = (s[i] >> 7) & 0xFF;
            if (e >= 0x8F || (e > 0 && e <= 0x60)) bad++;
        }
        atomicAdd(&cnt, bad);
        __syncthreads();
        if (threadIdx.x == 0) flags[blockIdx.x] = (cnt * 4 > n) ? 0 : 1;
    } else {
        __shared__ int vi32, vf32, vbf, vf16;
        if (threadIdx.x == 0) { vi32 = vf32 = vbf = vf16 = 0; }
        __syncthreads();
        int bi32 = 0, bf32 = 0, bbf = 0, bf16c = 0;
        for (int i = threadIdx.x; i < 4096; i += 256) {
            unsigned int w = mask[i];
            if (!(w == 0u || w == 1u)) bi32++;
            if (!(w == 0u || w == 0x3F800000u)) bf32++;
            unsigned int h0 = w & 0xFFFFu, h1 = w >> 16;
            if (!((h0 == 0u || h0 == 0x3F80u) && (h1 == 0u || h1 == 0x3F80u))) bbf++;
            if (!((h0 == 0u || h0 == 0x3C00u) && (h1 == 0u || h1 == 0x3C00u))) bf16c++;
        }
        if (bi32) atomicAdd(&vi32, 1);
        if (bf32) atomicAdd(&vf32, 1);
        if (bbf)  atomicAdd(&vbf, 1);
        if (bf16c) atomicAdd(&vf16, 1);
        __syncthreads();
        if (threadIdx.x == 0) {
            int w;
            if (vi32 == 0) w = 4;
            else if (vf32 == 0) w = 4;
            else if (vbf == 0) w = 2;
            else if (vf16 == 0) w = 2;
            else w = 1;
            flags[16] = w;
        }
    }
}

// ---------------------------------------------------------------------------
struct Ptr4 { const void* p[4]; };
struct ConvSrc { const void* kern[3]; const void* cb[3]; const void* gate[3]; };

// ---------------------------------------------------------------------------
// k_prep: fused converts + conv params. Grid 2561 x 256 thr.
//   [0, 2048)   qh|mh -> fp16 (2^22 16B-quanta total; 2048 quanta/block)
//   [2048,2560) 4 weight mats (2^18 quanta/tensor; 128 blocks/tensor)
//   [2560]      conv params
// fp32 path: thread t owns quanta {base + k*256} (lane-stride 16B = DENSE
// per instruction), 8 loads issued before a compiler fence, then 8B DENSE
// stores (quantum q -> 4 fp16 at dst4[q]). bf16 path: 4 dense 16B chunks.
__global__ void k_prep(const void* __restrict__ qh, const void* __restrict__ mh,
                       _Float16* __restrict__ h16dst,
                       Ptr4 wsrc, _Float16* __restrict__ w16dst,
                       ConvSrc cs, _Float16* __restrict__ par16,
                       float* __restrict__ tgf,
                       const int* __restrict__ flags) {
    const int bid = blockIdx.x, tid = threadIdx.x;
    if (bid < 2560) {
        const void* src;
        _Float16* dst;
        size_t gq, qmask, blk;
        int isBf;
        if (bid < 2048) {
            const int seg = bid >> 10;
            src = seg ? mh : qh;
            isBf = flags[seg];
            blk = (size_t)bid;
            gq = blk * 2048 + tid;             // global quantum (dst-contig)
            qmask = 2097151;                   // 2^21-1 (per-tensor src wrap)
            dst = h16dst;
        } else {
            const int lb = bid - 2048;
            const int seg = lb >> 7;
            src = wsrc.p[seg];
            isBf = flags[2 + seg];
            blk = (size_t)lb;
            gq = blk * 2048 + tid;
            qmask = 262143;                    // 2^18-1
            dst = w16dst;
        }
        if (isBf) {
            // bf16 src: one 16B chunk = 8 bf16 (already dense). 4 chunks/thr.
            size_t cb = blk * 1024 + tid;
            size_t cmask = qmask >> 1;
            const unsigned short* sp = (const unsigned short*)src;
            us8 s[4];
#pragma unroll
            for (int k = 0; k < 4; ++k)
                s[k] = *(const us8*)(sp + ((cb + (size_t)k * 256) & cmask) * 8);
            asm volatile("" ::: "memory");
#pragma unroll
            for (int k = 0; k < 4; ++k) {
                h8 d;
#pragma unroll
                for (int u = 0; u < 8; ++u) d[u] = (_Float16)bf2f(s[k][u]);
                *(h8*)(dst + (cb + (size_t)k * 256) * 8) = d;
            }
        } else {
            const f4_t* fp = (const f4_t*)src;
            h4* dst4 = (h4*)dst;
            f4_t v[8];
#pragma unroll
            for (int k = 0; k < 8; ++k)
                v[k] = fp[(gq + (size_t)k * 256) & qmask];
            asm volatile("" ::: "memory");
#pragma unroll
            for (int k = 0; k < 8; ++k) {
                h4 d;
#pragma unroll
                for (int u = 0; u < 4; ++u) d[u] = (_Float16)v[k][u];
                dst4[gq + (size_t)k * 256] = d;
            }
        }
    } else {
        const int D = 1024;
#pragma unroll
        for (int t = 0; t < 3; ++t) {
            const int kIs = flags[6 + t], cIs = flags[13 + t];
            for (int d = tid; d < D; d += 256) {
#pragma unroll
                for (int j = 0; j < 3; ++j)
                    par16[t * 3 * D + j * D + d] = (_Float16)rd(cs.kern[t], (long)d * 3 + j, kIs);
                par16[9 * D + t * D + d] = (_Float16)rd(cs.cb[t], d, cIs);
            }
        }
        if (tid < 3) {
            const void* g = cs.gate[tid];
            float gv = rd(g, 0, ((const unsigned int*)g)[0] == 0u ? 1 : 0);
            tgf[tid] = tanhf(gv);
        }
    }
}

// ---------------------------------------------------------------------------
// R10 NT GEMM (proven 753 TF class), MTILE x 128 x BK=64, 4 waves/block,
// 24KB LDS -> 4 blocks/CU with __launch_bounds__(256,4).
// MODE 0: fp16 out  MODE 1: fp16 out + bias  MODE 2: fp32 out + bias
template <int MODE, int MTILE>
__global__ __launch_bounds__(256, 4) void k_gemm_nt(
    const _Float16* __restrict__ A, const _Float16* __restrict__ Bm,
    void* __restrict__ Cout,
    const void* __restrict__ bias, const int* __restrict__ biasFlag,
    const void* __restrict__ bias2, const int* __restrict__ biasFlag2,
    int N, int K, long sA, long sB, long sC,
    int NT, int BZ) {

    constexpr int NI = (MTILE == 128) ? 4 : 2;
    constexpr int NCA = MTILE / 32;
    __shared__ __align__(16) _Float16 As[MTILE * 64];
    __shared__ __align__(16) _Float16 Bs[128 * 64];

    const long id = blockIdx.x;
    const int xcd = (int)(id & 7);
    const long local = id >> 3;
    const int col = (int)(local % NT);
    const long g = (local / NT) * 8 + xcd;
    const int bz = (int)(g % BZ);
    const int brow = (int)(g / BZ);

    const int tid  = threadIdx.x;
    const int wave = tid >> 6, lane = tid & 63;
    const int wm = (wave >> 1) * (MTILE / 2), wn = (wave & 1) * 64;
    const int lr = lane & 15, lq = lane >> 4;

    const _Float16* Ab = A + (long)bz * sA + (size_t)brow * MTILE * K;
    const _Float16* Bb = Bm + (long)bz * sB + (size_t)col * 128 * K;

    f4_t acc[NI][4] = {};

    const _Float16* gA[NCA];
    _Float16* lA[NCA];
#pragma unroll
    for (int j = 0; j < NCA; ++j) {
        int c = tid + j * 256;
        int r = c >> 3, s = ((c & 7) - r) & 7;
        gA[j] = Ab + (size_t)r * K + s * 8;
        lA[j] = As + c * 8;
    }
    const _Float16* gB[4];
    _Float16* lB[4];
#pragma unroll
    for (int j = 0; j < 4; ++j) {
        int c = tid + j * 256;
        int r = c >> 3, s = ((c & 7) - r) & 7;
        gB[j] = Bb + (size_t)r * K + s * 8;
        lB[j] = Bs + c * 8;
    }

    for (int kb = 0; kb < K; kb += 64) {
#pragma unroll
        for (int j = 0; j < NCA; ++j)
            __builtin_amdgcn_global_load_lds((void GLOBAL_AS*)(gA[j] + kb), (void LDS_AS*)lA[j], 16, 0, 0);
#pragma unroll
        for (int j = 0; j < 4; ++j)
            __builtin_amdgcn_global_load_lds((void GLOBAL_AS*)(gB[j] + kb), (void LDS_AS*)lB[j], 16, 0, 0);
        __syncthreads();

#pragma unroll
        for (int t = 0; t < 2; ++t) {
            const int fs = ((t * 4 + lq + lr) & 7) * 8;
            h8 af[NI], bfr[4];
#pragma unroll
            for (int i = 0; i < NI; ++i) af[i]  = *(const h8*)&As[(wm + i * 16 + lr) * 64 + fs];
#pragma unroll
            for (int j = 0; j < 4; ++j) bfr[j] = *(const h8*)&Bs[(wn + j * 16 + lr) * 64 + fs];
#pragma unroll
            for (int i = 0; i < NI; ++i)
#pragma unroll
                for (int j = 0; j < 4; ++j)
                    acc[i][j] = __builtin_amdgcn_mfma_f32_16x16x32_f16(af[i], bfr[j], acc[i][j], 0, 0, 0);
        }
        __syncthreads();
    }

    const long row0 = (long)brow * MTILE + wm + lq * 4;
    const long col0 = (long)col * 128 + wn + lr;

    float bv[4];
    if constexpr (MODE != 0) {
        const void* bp = bias; const int* bfp = biasFlag; long boff = 0;
        if (bias2 != nullptr && col * 128 >= (N >> 1)) {
            bp = bias2; bfp = biasFlag2; boff = (long)(N >> 1);
        }
        const int bIs = *bfp;
#pragma unroll
        for (int j = 0; j < 4; ++j) bv[j] = rd(bp, col0 + j * 16 - boff, bIs);
    } else {
#pragma unroll
        for (int j = 0; j < 4; ++j) bv[j] = 0.0f;
    }
    if constexpr (MODE == 2) {
        float* C = (float*)Cout + (long)bz * sC;
#pragma unroll
        for (int i = 0; i < NI; ++i)
#pragma unroll
            for (int j = 0; j < 4; ++j)
#pragma unroll
                for (int r = 0; r < 4; ++r)
                    C[(row0 + i * 16 + r) * (long)N + col0 + j * 16] = acc[i][j][r] + bv[j];
    } else {
        _Float16* C = (_Float16*)Cout + (long)bz * sC;
#pragma unroll
        for (int i = 0; i < NI; ++i)
#pragma unroll
            for (int j = 0; j < 4; ++j)
#pragma unroll
                for (int r = 0; r < 4; ++r) {
                    float v = acc[i][j][r] + bv[j];
                    v = fminf(fmaxf(v, -65000.0f), 65000.0f);
                    C[(row0 + i * 16 + r) * (long)N + col0 + j * 16] = (_Float16)v;
                }
    }
}

// ---------------------------------------------------------------------------
// m201-family pipelined NT GEMM: 256 x 256 x BK=64, 512 thr = 8 waves (2Mx4N),
// wave out 128x64. 128KB LDS, 2 K-tile buffers, 4 phases/K-tile (C-quadrants
// of 16 MFMA), 2 global_load_lds per phase, counted vmcnt(4) at 3/4 phase
// closes (never 0 until final drain), setprio(1) around MFMA, seg-rotation
// swizzle (measured 0 conflicts). R13-verified loop.
// MODE 1: fp16 out + bias (bias2 = 2nd N-half)
// MODE 3: fp16 scores, scale+clamp only (mask applied later in softmax)
template <int MODE>
__global__ __launch_bounds__(512, 2) void k_gemm16(
    const _Float16* __restrict__ A, const _Float16* __restrict__ Bm,
    void* __restrict__ Cout,
    const void* __restrict__ bias, const int* __restrict__ biasFlag,
    const void* __restrict__ bias2, const int* __restrict__ biasFlag2,
    int N, int K, long sA, long sB, long sC,
    float scale, int NT, int BZ) {

    __shared__ __align__(16) _Float16 AS[2][2][8192];
    __shared__ __align__(16) _Float16 BS[2][2][8192];

    const long id = blockIdx.x;
    const int xcd = (int)(id & 7);
    const long local = id >> 3;
    const int col = (int)(local % NT);
    const long g = (local / NT) * 8 + xcd;
    const int bz = (int)(g % BZ);
    const int brow = (int)(g / BZ);

    const int tid  = threadIdx.x;
    const int wave = tid >> 6, lane = tid & 63;
    const int wr = wave >> 2, wc = wave & 3;
    const int lr = lane & 15, lq = lane >> 4;

    const _Float16* Ab = A + (long)bz * sA + (size_t)brow * 256 * K;
    const _Float16* Bb = Bm + (long)bz * sB + (size_t)col * 256 * K;

    f4_t acc[8][4] = {};

    const _Float16* gAsrc[2][2];
    const _Float16* gBsrc[2][2];
    int lOff[2];
#pragma unroll
    for (int j = 0; j < 2; ++j) {
        int c = tid + j * 512;
        int rho = c >> 3, s = ((c & 7) - rho) & 7;
        lOff[j] = c * 8;
#pragma unroll
        for (int gg = 0; gg < 2; ++gg) {
            int ra = gg * 64 + (rho & 63) + (rho >> 6) * 128;
            gAsrc[gg][j] = Ab + (size_t)ra * K + s * 8;
            int rb = gg * 32 + (rho & 31) + (rho >> 5) * 64;
            gBsrc[gg][j] = Bb + (size_t)rb * K + s * 8;
        }
    }

#define STAGE_A(buf, gg, kb)                                                              \
    do {                                                                                  \
        __builtin_amdgcn_global_load_lds((void GLOBAL_AS*)(gAsrc[gg][0] + (kb)),          \
                                         (void LDS_AS*)&AS[buf][gg][lOff[0]], 16, 0, 0);  \
        __builtin_amdgcn_global_load_lds((void GLOBAL_AS*)(gAsrc[gg][1] + (kb)),          \
                                         (void LDS_AS*)&AS[buf][gg][lOff[1]], 16, 0, 0);  \
    } while (0)
#define STAGE_B(buf, gg, kb)                                                              \
    do {                                                                                  \
        __builtin_amdgcn_global_load_lds((void GLOBAL_AS*)(gBsrc[gg][0] + (kb)),          \
                                         (void LDS_AS*)&BS[buf][gg][lOff[0]], 16, 0, 0);  \
        __builtin_amdgcn_global_load_lds((void GLOBAL_AS*)(gBsrc[gg][1] + (kb)),          \
                                         (void LDS_AS*)&BS[buf][gg][lOff[1]], 16, 0, 0);  \
    } while (0)

    const int nkt = K >> 6;

    STAGE_A(0, 0, 0);
    STAGE_B(0, 0, 0);
    STAGE_B(0, 1, 0);
    STAGE_A(0, 1, 0);
    asm volatile("s_waitcnt vmcnt(4)" ::: "memory");
    __builtin_amdgcn_s_barrier();

    int cur = 0;
    for (int t = 0; t < nkt; ++t) {
        const bool pf = (t + 1) < nkt;
        const long kb = (long)(t + 1) << 6;
        const int nx = cur ^ 1;
        h8 a0[4][2], a1[4][2], b0[2][2], b1[2][2];

        // ---- phase 0: quadrant (0,0) ----
#pragma unroll
        for (int ks = 0; ks < 2; ++ks) {
#pragma unroll
            for (int m = 0; m < 4; ++m) {
                int rho = wr * 64 + m * 16 + lr;
                a0[m][ks] = *(const h8*)&AS[cur][0][rho * 64 + ((ks * 4 + lq + rho) & 7) * 8];
            }
#pragma unroll
            for (int n = 0; n < 2; ++n) {
                int rho = wc * 32 + n * 16 + lr;
                b0[n][ks] = *(const h8*)&BS[cur][0][rho * 64 + ((ks * 4 + lq + rho) & 7) * 8];
            }
        }
        if (pf) STAGE_A(nx, 0, kb);
        __builtin_amdgcn_s_barrier();
        __builtin_amdgcn_s_setprio(1);
#pragma unroll
        for (int ks = 0; ks < 2; ++ks)
#pragma unroll
            for (int m = 0; m < 4; ++m)
#pragma unroll
                for (int n = 0; n < 2; ++n)
                    acc[m][n] = __builtin_amdgcn_mfma_f32_16x16x32_f16(
                        a0[m][ks], b0[n][ks], acc[m][n], 0, 0, 0);
        __builtin_amdgcn_s_setprio(0);
        if (pf) asm volatile("s_waitcnt vmcnt(4)" ::: "memory");
        else    asm volatile("s_waitcnt vmcnt(2)" ::: "memory");
        __builtin_amdgcn_s_barrier();

        // ---- phase 1: quadrant (0,1) ----
#pragma unroll
        for (int ks = 0; ks < 2; ++ks)
#pragma unroll
            for (int n = 0; n < 2; ++n) {
                int rho = wc * 32 + n * 16 + lr;
                b1[n][ks] = *(const h8*)&BS[cur][1][rho * 64 + ((ks * 4 + lq + rho) & 7) * 8];
            }
        if (pf) STAGE_B(nx, 0, kb);
        __builtin_amdgcn_s_barrier();
        __builtin_amdgcn_s_setprio(1);
#pragma unroll
        for (int ks = 0; ks < 2; ++ks)
#pragma unroll
            for (int m = 0; m < 4; ++m)
#pragma unroll
                for (int n = 0; n < 2; ++n)
                    acc[m][2 + n] = __builtin_amdgcn_mfma_f32_16x16x32_f16(
                        a0[m][ks], b1[n][ks], acc[m][2 + n], 0, 0, 0);
        __builtin_amdgcn_s_setprio(0);
        if (pf) asm volatile("s_waitcnt vmcnt(4)" ::: "memory");
        else    asm volatile("s_waitcnt vmcnt(0)" ::: "memory");
        __builtin_amdgcn_s_barrier();

        // ---- phase 2: quadrant (1,1) ----
#pragma unroll
        for (int ks = 0; ks < 2; ++ks)
#pragma unroll
            for (int m = 0; m < 4; ++m) {
                int rho = wr * 64 + m * 16 + lr;
                a1[m][ks] = *(const h8*)&AS[cur][1][rho * 64 + ((ks * 4 + lq + rho) & 7) * 8];
            }
        if (pf) STAGE_B(nx, 1, kb);
        __builtin_amdgcn_s_barrier();
        __builtin_amdgcn_s_setprio(1);
#pragma unroll
        for (int ks = 0; ks < 2; ++ks)
#pragma unroll
            for (int m = 0; m < 4; ++m)
#pragma unroll
                for (int n = 0; n < 2; ++n)
                    acc[4 + m][2 + n] = __builtin_amdgcn_mfma_f32_16x16x32_f16(
                        a1[m][ks], b1[n][ks], acc[4 + m][2 + n], 0, 0, 0);
        __builtin_amdgcn_s_setprio(0);
        __builtin_amdgcn_s_barrier();

        // ---- phase 3: quadrant (1,0) ----
#pragma unroll
        for (int ks = 0; ks < 2; ++ks)
#pragma unroll
            for (int n = 0; n < 2; ++n) {
                int rho = wc * 32 + n * 16 + lr;
                b0[n][ks] = *(const h8*)&BS[cur][0][rho * 64 + ((ks * 4 + lq + rho) & 7) * 8];
            }
        if (pf) STAGE_A(nx, 1, kb);
        __builtin_amdgcn_s_barrier();
        __builtin_amdgcn_s_setprio(1);
#pragma unroll
        for (int ks = 0; ks < 2; ++ks)
#pragma unroll
            for (int m = 0; m < 4; ++m)
#pragma unroll
                for (int n = 0; n < 2; ++n)
                    acc[4 + m][n] = __builtin_amdgcn_mfma_f32_16x16x32_f16(
                        a1[m][ks], b0[n][ks], acc[4 + m][n], 0, 0, 0);
        __builtin_amdgcn_s_setprio(0);
        if (pf) asm volatile("s_waitcnt vmcnt(4)" ::: "memory");
        __builtin_amdgcn_s_barrier();
        cur = nx;
    }
#undef STAGE_A
#undef STAGE_B

    const long row0 = (long)brow * 256 + wr * 128 + lq * 4;
    const long col0 = (long)col * 256 + wc * 64 + lr;

    if constexpr (MODE == 3) {
        _Float16* C = (_Float16*)Cout + (long)bz * sC;
#pragma unroll
        for (int i = 0; i < 8; ++i)
#pragma unroll
            for (int j = 0; j < 4; ++j)
#pragma unroll
                for (int r = 0; r < 4; ++r) {
                    float v = acc[i][j][r] * scale;
                    v = fminf(fmaxf(v, -60000.0f), 60000.0f);
                    C[(row0 + i * 16 + r) * (long)N + col0 + j * 16] = (_Float16)v;
                }
    } else {
        float bv[4];
        {
            const void* bp = bias; const int* bfp = biasFlag; long boff = 0;
            if (bias2 != nullptr && col * 256 >= (N >> 1)) {
                bp = bias2; bfp = biasFlag2; boff = (long)(N >> 1);
            }
            const int bIs = *bfp;
#pragma unroll
            for (int j = 0; j < 4; ++j) bv[j] = rd(bp, col0 + j * 16 - boff, bIs);
        }
        _Float16* C = (_Float16*)Cout + (long)bz * sC;
#pragma unroll
        for (int i = 0; i < 8; ++i)
#pragma unroll
            for (int j = 0; j < 4; ++j)
#pragma unroll
                for (int r = 0; r < 4; ++r) {
                    float v = acc[i][j][r] + bv[j];
                    v = fminf(fmaxf(v, -65000.0f), 65000.0f);
                    C[(row0 + i * 16 + r) * (long)N + col0 + j * 16] = (_Float16)v;
                }
    }
}

// ---------------------------------------------------------------------------
// Fused conv launch.
// Blocks [0,4096): dwconv q (0..2047) / k (2048..4095), 4 rows/block:
//   thread-group g=tid>>7 handles rows s, s+1 (s = sp*4 + 2g) via 4 row loads
//   x[s-1..s+2] -> 2 outputs (ILP + 33% fewer loads).
// Blocks [4096,6144): dwconv_v + transpose.
struct ConvP {
    const _Float16* x; int xs; _Float16* y;
    const _Float16* kp; const _Float16* cb; const float* tg;
};
__global__ void k_convs(ConvP p0, ConvP p1,
                        const _Float16* __restrict__ xv, int xvs,
                        _Float16* __restrict__ vt,
                        const _Float16* __restrict__ kpv,
                        const _Float16* __restrict__ cbv,
                        const float* __restrict__ tgv,
                        int S, int SK, int D) {
    __shared__ _Float16 T[64][65];
    const int bid = blockIdx.x, tid = threadIdx.x;
    h8 zero;
#pragma unroll
    for (int u = 0; u < 8; ++u) zero[u] = (_Float16)0.0f;

    if (bid < 4096) {
        const ConvP& p = (bid >= 2048) ? p1 : p0;
        int l = bid & 2047;
        int b = l >> 9, sp = l & 511;
        int g = tid >> 7;
        int s = sp * 4 + g * 2;
        int d0 = (tid & 127) * 8;
        const size_t rs = p.xs;
        const size_t xb = ((size_t)b * S + s) * rs + d0;
        h8 xA = (s > 0) ? *(const h8*)(p.x + xb - rs) : zero;
        h8 xB = *(const h8*)(p.x + xb);
        h8 xC = *(const h8*)(p.x + xb + rs);
        h8 xD = (s + 2 < S) ? *(const h8*)(p.x + xb + 2 * rs) : zero;
        h8 k0 = *(const h8*)(p.kp + 0 * D + d0);
        h8 k1 = *(const h8*)(p.kp + 1 * D + d0);
        h8 k2 = *(const h8*)(p.kp + 2 * D + d0);
        h8 cb = *(const h8*)(p.cb + d0);
        float tg = *p.tg;
        h8 o0, o1;
#pragma unroll
        for (int u = 0; u < 8; ++u) {
            float c0 = (float)xA[u] * (float)k0[u] + (float)xB[u] * (float)k1[u] +
                       (float)xC[u] * (float)k2[u] + (float)cb[u];
            float v0 = (float)xB[u] + tg * c0;
            o0[u] = (_Float16)fminf(fmaxf(v0, -65000.0f), 65000.0f);
            float c1 = (float)xB[u] * (float)k0[u] + (float)xC[u] * (float)k1[u] +
                       (float)xD[u] * (float)k2[u] + (float)cb[u];
            float v1 = (float)xC[u] + tg * c1;
            o1[u] = (_Float16)fminf(fmaxf(v1, -65000.0f), 65000.0f);
        }
        const size_t yb = ((size_t)b * S + s) * D + d0;
        *(h8*)(p.y + yb) = o0;
        *(h8*)(p.y + yb + D) = o1;
    } else {
        int l = bid - 4096;
        int bx = l & 31, by = (l >> 5) & 15, b = l >> 9;
        int s0 = bx * 64, d0 = by * 64;
        float tg = *tgv;
#pragma unroll
        for (int it = 0; it < 2; ++it) {
            int idx = it * 256 + tid;
            int r = idx >> 3, c = (idx & 7) * 8;
            int s = s0 + r;
            const size_t xb = ((size_t)b * SK + s) * xvs + d0 + c;
            h8 xc = *(const h8*)(xv + xb);
            h8 xp = (s > 0)      ? *(const h8*)(xv + xb - xvs) : zero;
            h8 xn = (s < SK - 1) ? *(const h8*)(xv + xb + xvs) : zero;
            h8 k0 = *(const h8*)(kpv + 0 * D + d0 + c);
            h8 k1 = *(const h8*)(kpv + 1 * D + d0 + c);
            h8 k2 = *(const h8*)(kpv + 2 * D + d0 + c);
            h8 cb = *(const h8*)(cbv + d0 + c);
#pragma unroll
            for (int u = 0; u < 8; ++u) {
                float cv = (float)xp[u] * (float)k0[u] + (float)xc[u] * (float)k1[u] +
                           (float)xn[u] * (float)k2[u] + (float)cb[u];
                float v = (float)xc[u] + tg * cv;
                T[r][c + u] = (_Float16)fminf(fmaxf(v, -65000.0f), 65000.0f);
            }
        }
        __syncthreads();
#pragma unroll
        for (int it = 0; it < 2; ++it) {
            int idx = it * 256 + tid;
            int dr = idx >> 3, c = (idx & 7) * 8;
            h8 o;
#pragma unroll
            for (int u = 0; u < 8; ++u) o[u] = T[c + u][dr];
            *(h8*)(vt + ((size_t)b * D + d0 + dr) * SK + s0 + c) = o;
        }
    }
}

// ---------------------------------------------------------------------------
// Row softmax + mask. Block bid = MASK row (0..2047); wave w = batch b.
// All 4 waves share mask row bid -> mask traffic /4 (L1/L2-hot for waves 1-3).
// Lane owns 4 interleaved h8 chunks (chunk c = j*64+lane, dense 16B/lane).
// Pure __shfl_xor 64-lane reduction: no LDS, no __syncthreads.
__global__ __launch_bounds__(256) void k_softmax(const _Float16* __restrict__ sc,
                                                 _Float16* __restrict__ pr,
                                                 const void* __restrict__ mraw,
                                                 const int* __restrict__ mwf,
                                                 int SK) {
    const int w = threadIdx.x >> 6;               // batch
    const long row = (long)w * 2048 + blockIdx.x; // scores row (b*SQ + r)
    const int lane = threadIdx.x & 63;
    const long rb = row * (long)SK;
    const long mrb = (long)blockIdx.x * SK;
    const int mw = *mwf;

    h8 v[4];
#pragma unroll
    for (int j = 0; j < 4; ++j)
        v[j] = *(const h8*)(sc + rb + (size_t)(j * 64 + lane) * 8);

    unsigned int km[4];
    if (mw == 4) {
#pragma unroll
        for (int j = 0; j < 4; ++j) {
            const unsigned int* mp = (const unsigned int*)mraw + mrb + (size_t)(j * 64 + lane) * 8;
            u32x4 m0 = *(const u32x4*)mp;
            u32x4 m1 = *(const u32x4*)(mp + 4);
            unsigned int k = 0;
#pragma unroll
            for (int u = 0; u < 4; ++u) {
                k |= (m0[u] != 0u) ? (1u << u) : 0u;
                k |= (m1[u] != 0u) ? (1u << (4 + u)) : 0u;
            }
            km[j] = k;
        }
    } else if (mw == 2) {
#pragma unroll
        for (int j = 0; j < 4; ++j) {
            us8 m8 = *(const us8*)((const unsigned short*)mraw + mrb + (size_t)(j * 64 + lane) * 8);
            unsigned int k = 0;
#pragma unroll
            for (int u = 0; u < 8; ++u) k |= (m8[u] != 0) ? (1u << u) : 0u;
            km[j] = k;
        }
    } else {
#pragma unroll
        for (int j = 0; j < 4; ++j) {
            unsigned long long m = *(const unsigned long long*)
                ((const unsigned char*)mraw + mrb + (size_t)(j * 64 + lane) * 8);
            unsigned int k = 0;
#pragma unroll
            for (int u = 0; u < 8; ++u) k |= ((m >> (8 * u)) & 0xFFull) ? (1u << u) : 0u;
            km[j] = k;
        }
    }

    float f[4][8];
    float mx = -3.0e38f;
#pragma unroll
    for (int j = 0; j < 4; ++j)
#pragma unroll
        for (int u = 0; u < 8; ++u) {
            f[j][u] = (km[j] & (1u << u)) ? (float)v[j][u] : -60000.0f;
            mx = fmaxf(mx, f[j][u]);
        }
#pragma unroll
    for (int o = 32; o > 0; o >>= 1) mx = fmaxf(mx, __shfl_xor(mx, o, 64));

    float sum = 0.0f;
#pragma unroll
    for (int j = 0; j < 4; ++j)
#pragma unroll
        for (int u = 0; u < 8; ++u) { f[j][u] = __expf(f[j][u] - mx); sum += f[j][u]; }
#pragma unroll
    for (int o = 32; o > 0; o >>= 1) sum += __shfl_xor(sum, o, 64);
    const float inv = 1.0f / sum;

#pragma unroll
    for (int j = 0; j < 4; ++j) {
        h8 o8;
#pragma unroll
        for (int u = 0; u < 8; ++u) o8[u] = (_Float16)(f[j][u] * inv);
        *(h8*)(pr + rb + (size_t)(j * 64 + lane) * 8) = o8;
    }
}

// ---------------------------------------------------------------------------
extern "C" void kernel_launch(void* const* d_in, const int* in_sizes, int n_in,
                              void* d_out, int out_size, void* d_ws, size_t ws_size,
                              hipStream_t stream) {
    const int Bn = 4, SQ = 2048, SK = 2048, D = 1024;
    const size_t nQ = (size_t)Bn * SQ * D;   // 8,388,608

    const void* qh = d_in[0];
    const void* mh = d_in[1];
    const void* mask = d_in[2];
    const void* q_w = d_in[3];
    const void* q_b = d_in[4];
    const void* k_w = d_in[5];
    const void* k_b = d_in[6];
    const void* v_w = d_in[7];
    const void* v_b = d_in[8];
    const void* o_w = d_in[9];
    const void* o_b = d_in[10];
    const void* q_kern = d_in[11];
    const void* q_cb   = d_in[12];
    const void* q_g    = d_in[13];
    const void* k_kern = d_in[14];
    const void* k_cb   = d_in[15];
    const void* k_g    = d_in[16];
    const void* v_kern = d_in[17];
    const void* v_cb   = d_in[18];
    const void* v_g    = d_in[19];

    // ---- workspace layout (lifetime-overlaid) ----
    // [0,33.5MB)        scores -> attn_out; par16/tgf live in the last 32KB
    //                   of this region from step 1 until k_convs (step 3),
    //                   clobbered only when scores is written (step 5)
    // [33.5,41.9MB)     w16 x4
    // [41.9,92.3MB)     lin_q + lin_kv; probs overlays after convs
    // [92.3,125.8MB)    qh16/mh16 staging -> conv_q, conv_k
    // [125.8,142.6MB)   vt  (must NOT alias lin_kv)
    // [142.6MB+)        flags
    char* ws = (char*)d_ws;
    _Float16* scores   = (_Float16*)(ws + 0);
    _Float16* attn_out = (_Float16*)(ws + 0);
    _Float16* par16    = (_Float16*)(ws + 33521664);          // 33.5MB - 32KB
    float*    tgf      = (float*)(ws + 33521664 + 24576);
    _Float16* w16      = (_Float16*)(ws + 33554432);
    _Float16* lin      = (_Float16*)(ws + 41943040);
    _Float16* lin_q    = lin;
    _Float16* lin_kv   = lin + nQ;
    _Float16* probs    = lin;
    _Float16* conv     = (_Float16*)(ws + 92274688);
    _Float16* qh16     = conv;
    _Float16* mh16     = conv + nQ;
    _Float16* vt       = (_Float16*)(ws + 125829120);
    int*      flags    = (int*)(ws + 142606336);

    // 0. probes
    Probe16 pa;
    const void* pp[16] = {qh, mh, q_w, k_w, v_w, o_w, q_kern, k_kern, v_kern,
                          q_b, k_b, v_b, o_b, q_cb, k_cb, v_cb};
    const int   pn[16] = {2048, 2048, 2048, 2048, 2048, 2048, 3072, 3072, 3072,
                          1024, 1024, 1024, 1024, 1024, 1024, 1024};
    for (int i = 0; i < 16; ++i) { pa.p[i] = (const unsigned short*)pp[i]; pa.n[i] = pn[i]; }
    k_probes<<<17, 256, 0, stream>>>(pa, (const unsigned int*)mask, flags);

    // 1. fused converts + conv params (dense-instruction fp32 path)
    Ptr4 wp; wp.p[0] = q_w; wp.p[1] = k_w; wp.p[2] = v_w; wp.p[3] = o_w;
    ConvSrc cs;
    cs.kern[0] = q_kern; cs.kern[1] = k_kern; cs.kern[2] = v_kern;
    cs.cb[0] = q_cb; cs.cb[1] = k_cb; cs.cb[2] = v_cb;
    cs.gate[0] = q_g; cs.gate[1] = k_g; cs.gate[2] = v_g;
    k_prep<<<2561, 256, 0, stream>>>(qh, mh, qh16, wp, w16, cs, par16, tgf, flags);

    // 2. projections
    k_gemm_nt<1, 64><<<dim3(1024), 256, 0, stream>>>(
        qh16, w16, lin_q, q_b, flags + 9, nullptr, nullptr,
        D, D, 0, 0, 0, 8, 1);
    k_gemm16<1><<<dim3(256), 512, 0, stream>>>(
        mh16, w16 + (size_t)D * D, lin_kv, k_b, flags + 10, v_b, flags + 11,
        2 * D, D, 0, 0, 0, 1.0f, 8, 1);

    // 3. all three gated depthwise convs in one launch (2 rows/thread)
    ConvP cq{lin_q, D, conv + 0 * nQ, par16 + 0 * 3 * D, par16 + 9 * D + 0 * D, tgf + 0};
    ConvP ck{lin_kv, 2 * D, conv + 1 * nQ, par16 + 1 * 3 * D, par16 + 9 * D + 1 * D, tgf + 1};
    k_convs<<<dim3(6144), 256, 0, stream>>>(
        cq, ck, lin_kv + D, 2 * D, vt, par16 + 2 * 3 * D, par16 + 9 * D + 2 * D, tgf + 2,
        SQ, SK, D);

    // 5. scores: per-batch M=2048 (8 tiles), N=2048 (NT=8), BZ=4 -> 256 blocks
    k_gemm16<3><<<dim3(256), 512, 0, stream>>>(
        conv + 0 * nQ, conv + 1 * nQ, scores, nullptr, nullptr, nullptr, nullptr,
        SK, D, (long)SQ * D, (long)SK * D, (long)SQ * SK, 0.03125f, 8, 4);

    // 6. softmax + mask: block per mask row, 4 batch rows/block
    k_softmax<<<SQ, 256, 0, stream>>>(scores, probs, mask, flags + 16, SK);

    // 7. attn @ v: per-batch M=2048(64:32), N=1024 (NT=8), BZ=4 -> 1024 blocks
    k_gemm_nt<0, 64><<<dim3(1024), 256, 0, stream>>>(
        probs, vt, attn_out, nullptr, nullptr, nullptr, nullptr,
        D, SK, (long)SQ * SK, (long)D * SK, (long)SQ * D, 8, 4);

    // 8. out-proj: M=8192(64:128), N=1024 (NT=8), BZ=1 -> 1024 blocks, fp32 out
    k_gemm_nt<2, 64><<<dim3(1024), 256, 0, stream>>>(
        attn_out, w16 + 3 * (size_t)D * D, d_out, o_b, flags + 12, nullptr, nullptr,
        D, D, 0, 0, 0, 8, 1);

    (void)in_sizes; (void)n_in; (void)out_size; (void)ws_size;
}

// Round 10
// 382.585 us; speedup vs baseline: 1.0115x; 1.0115x over previous
//
#include <hip/hip_runtime.h>
#include <cstdint>
#include <cstddef>

// ---------------------------------------------------------------------------
// TransformConvCrossAttention: B=4, SQ=SK=2048, D=1024, Kconv=3
// fp16 compute, fp32 MFMA accumulation; fp32 in/out (runtime-verified).
// R20: R19 + probes launch merged into k_prep (9 -> 8 launches).
//   - convert blocks SELF-SNIFF dtype (2048 half-samples of own region,
//     LDS-consensus, same exponent heuristic/threshold as the old probe)
//   - conv-params block self-sniffs its 6 small tensors
//   - 5 tail blocks produce the only flags still consumed downstream:
//     bias flags [9..12] (GEMM epilogues) and mask width [16] (softmax)
//   GEMM / convs / softmax kernels byte-identical to R19.
// ---------------------------------------------------------------------------

#define GLOBAL_AS __attribute__((address_space(1)))
#define LDS_AS    __attribute__((address_space(3)))

typedef _Float16 h8 __attribute__((ext_vector_type(8)));
typedef _Float16 h4 __attribute__((ext_vector_type(4)));
typedef float    f4_t __attribute__((ext_vector_type(4)));
typedef unsigned short us8 __attribute__((ext_vector_type(8)));
typedef unsigned int u32x4 __attribute__((ext_vector_type(4)));

__device__ __forceinline__ float bf2f(unsigned short u) {
    union { unsigned int i; float f; } x; x.i = ((unsigned int)u) << 16; return x.f;
}
__device__ __forceinline__ float rd(const void* p, long i, int isBf) {
    return isBf ? bf2f(((const unsigned short*)p)[i]) : ((const float*)p)[i];
}
__device__ __forceinline__ int badHalf(unsigned int h) {
    int e = (int)((h >> 7) & 0xFF);
    return (e >= 0x8F || (e > 0 && e <= 0x60)) ? 1 : 0;
}

struct Ptr4 { const void* p[4]; };
struct ConvSrc { const void* kern[3]; const void* cb[3]; const void* gate[3]; };

// ---------------------------------------------------------------------------
// k_prep: fused dtype-probes + converts + conv params. Grid 2566 x 256 thr.
//   [0, 2048)   qh|mh -> fp16 (2^21 16B-src-quanta/tensor in fp32 terms)
//   [2048,2560) 4 weight mats (2^18 quanta/tensor; 128 blocks/tensor)
//   [2560]      conv params (self-sniffed)
//   [2561,2565) bias dtype probes -> flags[9..12]
//   [2565]      mask width probe  -> flags[16]
// Convert blocks: block-consensus self-sniff (2048 half-samples from own
// region, bytes < min(bf16,fp32) size), then the R19-verified convert paths.
__global__ void k_prep(const void* __restrict__ qh, const void* __restrict__ mh,
                       _Float16* __restrict__ h16dst,
                       Ptr4 wsrc, _Float16* __restrict__ w16dst,
                       ConvSrc cs, _Float16* __restrict__ par16,
                       float* __restrict__ tgf,
                       Ptr4 bsrc, const unsigned int* __restrict__ mask,
                       int* __restrict__ flags) {
    __shared__ int s_cnt;
    __shared__ int vi32, vf32, vbf, vf16;
    const int bid = blockIdx.x, tid = threadIdx.x;

    if (bid < 2560) {
        const void* src;
        _Float16* dst;
        size_t gq, qmask, blk;
        if (bid < 2048) {
            const int seg = bid >> 10;
            src = seg ? mh : qh;
            blk = (size_t)bid;
            gq = blk * 2048 + tid;             // global quantum (dst-contig)
            qmask = 2097151;                   // 2^21-1 (per-tensor src wrap)
            dst = h16dst;
        } else {
            const int lb = bid - 2048;
            const int seg = lb >> 7;
            src = wsrc.p[seg];
            blk = (size_t)lb;
            gq = blk * 2048 + tid;
            qmask = 262143;                    // 2^18-1
            dst = w16dst;
        }
        // ---- block-consensus dtype sniff (2048 half-samples) ----
        if (tid == 0) s_cnt = 0;
        __syncthreads();
        {
            size_t cidx = (blk * 1024 + tid) & (qmask >> 1);  // bytes < bf16 size
            u32x4 w = *((const u32x4*)src + cidx);
            int bad = 0;
#pragma unroll
            for (int i = 0; i < 4; ++i) {
                bad += badHalf(w[i] & 0xFFFFu);
                bad += badHalf(w[i] >> 16);
            }
            if (bad) atomicAdd(&s_cnt, bad);
        }
        __syncthreads();
        const int isBf = !(s_cnt * 4 > 2048);

        if (isBf) {
            // bf16 src: one 16B chunk = 8 bf16 (already dense). 4 chunks/thr.
            size_t cb = blk * 1024 + tid;
            size_t cmask = qmask >> 1;
            const unsigned short* sp = (const unsigned short*)src;
            us8 s[4];
#pragma unroll
            for (int k = 0; k < 4; ++k)
                s[k] = *(const us8*)(sp + ((cb + (size_t)k * 256) & cmask) * 8);
            asm volatile("" ::: "memory");
#pragma unroll
            for (int k = 0; k < 4; ++k) {
                h8 d;
#pragma unroll
                for (int u = 0; u < 8; ++u) d[u] = (_Float16)bf2f(s[k][u]);
                *(h8*)(dst + (cb + (size_t)k * 256) * 8) = d;
            }
        } else {
            const f4_t* fp = (const f4_t*)src;
            h4* dst4 = (h4*)dst;
            f4_t v[8];
#pragma unroll
            for (int k = 0; k < 8; ++k)
                v[k] = fp[(gq + (size_t)k * 256) & qmask];
            asm volatile("" ::: "memory");
#pragma unroll
            for (int k = 0; k < 8; ++k) {
                h4 d;
#pragma unroll
                for (int u = 0; u < 4; ++u) d[u] = (_Float16)v[k][u];
                dst4[gq + (size_t)k * 256] = d;
            }
        }
    } else if (bid == 2560) {
        // ---- conv params, self-sniffed ----
        const int D = 1024;
        int kIsv[3], cIsv[3];
#pragma unroll
        for (int t = 0; t < 3; ++t) {
            // kern[t]: sample 2048 halves (bytes < 4096 <= bf16 size 6144)
            __syncthreads();
            if (tid == 0) s_cnt = 0;
            __syncthreads();
            {
                const unsigned short* ks = (const unsigned short*)cs.kern[t];
                int bad = 0;
#pragma unroll
                for (int i = 0; i < 8; ++i) bad += badHalf(ks[tid * 8 + i]);
                if (bad) atomicAdd(&s_cnt, bad);
            }
            __syncthreads();
            kIsv[t] = !(s_cnt * 4 > 2048);
            // cb[t]: sample 1024 halves (bytes < 2048 <= bf16 size 2048)
            __syncthreads();
            if (tid == 0) s_cnt = 0;
            __syncthreads();
            {
                const unsigned short* bs = (const unsigned short*)cs.cb[t];
                int bad = 0;
#pragma unroll
                for (int i = 0; i < 4; ++i) bad += badHalf(bs[tid * 4 + i]);
                if (bad) atomicAdd(&s_cnt, bad);
            }
            __syncthreads();
            cIsv[t] = !(s_cnt * 4 > 1024);
        }
#pragma unroll
        for (int t = 0; t < 3; ++t) {
            for (int d = tid; d < D; d += 256) {
#pragma unroll
                for (int j = 0; j < 3; ++j)
                    par16[t * 3 * D + j * D + d] = (_Float16)rd(cs.kern[t], (long)d * 3 + j, kIsv[t]);
                par16[9 * D + t * D + d] = (_Float16)rd(cs.cb[t], d, cIsv[t]);
            }
        }
        if (tid < 3) {
            const void* g = cs.gate[tid];
            float gv = rd(g, 0, ((const unsigned int*)g)[0] == 0u ? 1 : 0);
            tgf[tid] = tanhf(gv);
        }
    } else if (bid < 2565) {
        // ---- bias dtype probes -> flags[9..12] (consumed by later launches)
        const int idx = bid - 2561;
        const unsigned short* s = (const unsigned short*)bsrc.p[idx];
        if (tid == 0) s_cnt = 0;
        __syncthreads();
        int bad = 0;
        for (int i = tid; i < 1024; i += 256) bad += badHalf(s[i]);
        if (bad) atomicAdd(&s_cnt, bad);
        __syncthreads();
        if (tid == 0) flags[9 + idx] = (s_cnt * 4 > 1024) ? 0 : 1;
    } else {
        // ---- mask width probe -> flags[16] ----
        if (tid == 0) { vi32 = vf32 = vbf = vf16 = 0; }
        __syncthreads();
        int bi32 = 0, bf32 = 0, bbf = 0, bf16c = 0;
        for (int i = tid; i < 4096; i += 256) {
            unsigned int w = mask[i];
            if (!(w == 0u || w == 1u)) bi32++;
            if (!(w == 0u || w == 0x3F800000u)) bf32++;
            unsigned int h0 = w & 0xFFFFu, h1 = w >> 16;
            if (!((h0 == 0u || h0 == 0x3F80u) && (h1 == 0u || h1 == 0x3F80u))) bbf++;
            if (!((h0 == 0u || h0 == 0x3C00u) && (h1 == 0u || h1 == 0x3C00u))) bf16c++;
        }
        if (bi32) atomicAdd(&vi32, 1);
        if (bf32) atomicAdd(&vf32, 1);
        if (bbf)  atomicAdd(&vbf, 1);
        if (bf16c) atomicAdd(&vf16, 1);
        __syncthreads();
        if (tid == 0) {
            int w;
            if (vi32 == 0) w = 4;
            else if (vf32 == 0) w = 4;
            else if (vbf == 0) w = 2;
            else if (vf16 == 0) w = 2;
            else w = 1;
            flags[16] = w;
        }
    }
}

// ---------------------------------------------------------------------------
// R10 NT GEMM (proven 753 TF class), MTILE x 128 x BK=64, 4 waves/block,
// 24KB LDS -> 4 blocks/CU with __launch_bounds__(256,4).
// MODE 0: fp16 out  MODE 1: fp16 out + bias  MODE 2: fp32 out + bias
template <int MODE, int MTILE>
__global__ __launch_bounds__(256, 4) void k_gemm_nt(
    const _Float16* __restrict__ A, const _Float16* __restrict__ Bm,
    void* __restrict__ Cout,
    const void* __restrict__ bias, const int* __restrict__ biasFlag,
    const void* __restrict__ bias2, const int* __restrict__ biasFlag2,
    int N, int K, long sA, long sB, long sC,
    int NT, int BZ) {

    constexpr int NI = (MTILE == 128) ? 4 : 2;
    constexpr int NCA = MTILE / 32;
    __shared__ __align__(16) _Float16 As[MTILE * 64];
    __shared__ __align__(16) _Float16 Bs[128 * 64];

    const long id = blockIdx.x;
    const int xcd = (int)(id & 7);
    const long local = id >> 3;
    const int col = (int)(local % NT);
    const long g = (local / NT) * 8 + xcd;
    const int bz = (int)(g % BZ);
    const int brow = (int)(g / BZ);

    const int tid  = threadIdx.x;
    const int wave = tid >> 6, lane = tid & 63;
    const int wm = (wave >> 1) * (MTILE / 2), wn = (wave & 1) * 64;
    const int lr = lane & 15, lq = lane >> 4;

    const _Float16* Ab = A + (long)bz * sA + (size_t)brow * MTILE * K;
    const _Float16* Bb = Bm + (long)bz * sB + (size_t)col * 128 * K;

    f4_t acc[NI][4] = {};

    const _Float16* gA[NCA];
    _Float16* lA[NCA];
#pragma unroll
    for (int j = 0; j < NCA; ++j) {
        int c = tid + j * 256;
        int r = c >> 3, s = ((c & 7) - r) & 7;
        gA[j] = Ab + (size_t)r * K + s * 8;
        lA[j] = As + c * 8;
    }
    const _Float16* gB[4];
    _Float16* lB[4];
#pragma unroll
    for (int j = 0; j < 4; ++j) {
        int c = tid + j * 256;
        int r = c >> 3, s = ((c & 7) - r) & 7;
        gB[j] = Bb + (size_t)r * K + s * 8;
        lB[j] = Bs + c * 8;
    }

    for (int kb = 0; kb < K; kb += 64) {
#pragma unroll
        for (int j = 0; j < NCA; ++j)
            __builtin_amdgcn_global_load_lds((void GLOBAL_AS*)(gA[j] + kb), (void LDS_AS*)lA[j], 16, 0, 0);
#pragma unroll
        for (int j = 0; j < 4; ++j)
            __builtin_amdgcn_global_load_lds((void GLOBAL_AS*)(gB[j] + kb), (void LDS_AS*)lB[j], 16, 0, 0);
        __syncthreads();

#pragma unroll
        for (int t = 0; t < 2; ++t) {
            const int fs = ((t * 4 + lq + lr) & 7) * 8;
            h8 af[NI], bfr[4];
#pragma unroll
            for (int i = 0; i < NI; ++i) af[i]  = *(const h8*)&As[(wm + i * 16 + lr) * 64 + fs];
#pragma unroll
            for (int j = 0; j < 4; ++j) bfr[j] = *(const h8*)&Bs[(wn + j * 16 + lr) * 64 + fs];
#pragma unroll
            for (int i = 0; i < NI; ++i)
#pragma unroll
                for (int j = 0; j < 4; ++j)
                    acc[i][j] = __builtin_amdgcn_mfma_f32_16x16x32_f16(af[i], bfr[j], acc[i][j], 0, 0, 0);
        }
        __syncthreads();
    }

    const long row0 = (long)brow * MTILE + wm + lq * 4;
    const long col0 = (long)col * 128 + wn + lr;

    float bv[4];
    if constexpr (MODE != 0) {
        const void* bp = bias; const int* bfp = biasFlag; long boff = 0;
        if (bias2 != nullptr && col * 128 >= (N >> 1)) {
            bp = bias2; bfp = biasFlag2; boff = (long)(N >> 1);
        }
        const int bIs = *bfp;
#pragma unroll
        for (int j = 0; j < 4; ++j) bv[j] = rd(bp, col0 + j * 16 - boff, bIs);
    } else {
#pragma unroll
        for (int j = 0; j < 4; ++j) bv[j] = 0.0f;
    }
    if constexpr (MODE == 2) {
        float* C = (float*)Cout + (long)bz * sC;
#pragma unroll
        for (int i = 0; i < NI; ++i)
#pragma unroll
            for (int j = 0; j < 4; ++j)
#pragma unroll
                for (int r = 0; r < 4; ++r)
                    C[(row0 + i * 16 + r) * (long)N + col0 + j * 16] = acc[i][j][r] + bv[j];
    } else {
        _Float16* C = (_Float16*)Cout + (long)bz * sC;
#pragma unroll
        for (int i = 0; i < NI; ++i)
#pragma unroll
            for (int j = 0; j < 4; ++j)
#pragma unroll
                for (int r = 0; r < 4; ++r) {
                    float v = acc[i][j][r] + bv[j];
                    v = fminf(fmaxf(v, -65000.0f), 65000.0f);
                    C[(row0 + i * 16 + r) * (long)N + col0 + j * 16] = (_Float16)v;
                }
    }
}

// ---------------------------------------------------------------------------
// m201-family pipelined NT GEMM: 256 x 256 x BK=64, 512 thr = 8 waves (2Mx4N),
// wave out 128x64. 128KB LDS, 2 K-tile buffers, 4 phases/K-tile (C-quadrants
// of 16 MFMA), 2 global_load_lds per phase, counted vmcnt(4) at 3/4 phase
// closes (never 0 until final drain), setprio(1) around MFMA, seg-rotation
// swizzle (measured 0 conflicts). R13-verified loop.
// MODE 1: fp16 out + bias (bias2 = 2nd N-half)
// MODE 3: fp16 scores, scale+clamp only (mask applied later in softmax)
template <int MODE>
__global__ __launch_bounds__(512, 2) void k_gemm16(
    const _Float16* __restrict__ A, const _Float16* __restrict__ Bm,
    void* __restrict__ Cout,
    const void* __restrict__ bias, const int* __restrict__ biasFlag,
    const void* __restrict__ bias2, const int* __restrict__ biasFlag2,
    int N, int K, long sA, long sB, long sC,
    float scale, int NT, int BZ) {

    __shared__ __align__(16) _Float16 AS[2][2][8192];
    __shared__ __align__(16) _Float16 BS[2][2][8192];

    const long id = blockIdx.x;
    const int xcd = (int)(id & 7);
    const long local = id >> 3;
    const int col = (int)(local % NT);
    const long g = (local / NT) * 8 + xcd;
    const int bz = (int)(g % BZ);
    const int brow = (int)(g / BZ);

    const int tid  = threadIdx.x;
    const int wave = tid >> 6, lane = tid & 63;
    const int wr = wave >> 2, wc = wave & 3;
    const int lr = lane & 15, lq = lane >> 4;

    const _Float16* Ab = A + (long)bz * sA + (size_t)brow * 256 * K;
    const _Float16* Bb = Bm + (long)bz * sB + (size_t)col * 256 * K;

    f4_t acc[8][4] = {};

    const _Float16* gAsrc[2][2];
    const _Float16* gBsrc[2][2];
    int lOff[2];
#pragma unroll
    for (int j = 0; j < 2; ++j) {
        int c = tid + j * 512;
        int rho = c >> 3, s = ((c & 7) - rho) & 7;
        lOff[j] = c * 8;
#pragma unroll
        for (int gg = 0; gg < 2; ++gg) {
            int ra = gg * 64 + (rho & 63) + (rho >> 6) * 128;
            gAsrc[gg][j] = Ab + (size_t)ra * K + s * 8;
            int rb = gg * 32 + (rho & 31) + (rho >> 5) * 64;
            gBsrc[gg][j] = Bb + (size_t)rb * K + s * 8;
        }
    }

#define STAGE_A(buf, gg, kb)                                                              \
    do {                                                                                  \
        __builtin_amdgcn_global_load_lds((void GLOBAL_AS*)(gAsrc[gg][0] + (kb)),          \
                                         (void LDS_AS*)&AS[buf][gg][lOff[0]], 16, 0, 0);  \
        __builtin_amdgcn_global_load_lds((void GLOBAL_AS*)(gAsrc[gg][1] + (kb)),          \
                                         (void LDS_AS*)&AS[buf][gg][lOff[1]], 16, 0, 0);  \
    } while (0)
#define STAGE_B(buf, gg, kb)                                                              \
    do {                                                                                  \
        __builtin_amdgcn_global_load_lds((void GLOBAL_AS*)(gBsrc[gg][0] + (kb)),          \
                                         (void LDS_AS*)&BS[buf][gg][lOff[0]], 16, 0, 0);  \
        __builtin_amdgcn_global_load_lds((void GLOBAL_AS*)(gBsrc[gg][1] + (kb)),          \
                                         (void LDS_AS*)&BS[buf][gg][lOff[1]], 16, 0, 0);  \
    } while (0)

    const int nkt = K >> 6;

    STAGE_A(0, 0, 0);
    STAGE_B(0, 0, 0);
    STAGE_B(0, 1, 0);
    STAGE_A(0, 1, 0);
    asm volatile("s_waitcnt vmcnt(4)" ::: "memory");
    __builtin_amdgcn_s_barrier();

    int cur = 0;
    for (int t = 0; t < nkt; ++t) {
        const bool pf = (t + 1) < nkt;
        const long kb = (long)(t + 1) << 6;
        const int nx = cur ^ 1;
        h8 a0[4][2], a1[4][2], b0[2][2], b1[2][2];

        // ---- phase 0: quadrant (0,0) ----
#pragma unroll
        for (int ks = 0; ks < 2; ++ks) {
#pragma unroll
            for (int m = 0; m < 4; ++m) {
                int rho = wr * 64 + m * 16 + lr;
                a0[m][ks] = *(const h8*)&AS[cur][0][rho * 64 + ((ks * 4 + lq + rho) & 7) * 8];
            }
#pragma unroll
            for (int n = 0; n < 2; ++n) {
                int rho = wc * 32 + n * 16 + lr;
                b0[n][ks] = *(const h8*)&BS[cur][0][rho * 64 + ((ks * 4 + lq + rho) & 7) * 8];
            }
        }
        if (pf) STAGE_A(nx, 0, kb);
        __builtin_amdgcn_s_barrier();
        __builtin_amdgcn_s_setprio(1);
#pragma unroll
        for (int ks = 0; ks < 2; ++ks)
#pragma unroll
            for (int m = 0; m < 4; ++m)
#pragma unroll
                for (int n = 0; n < 2; ++n)
                    acc[m][n] = __builtin_amdgcn_mfma_f32_16x16x32_f16(
                        a0[m][ks], b0[n][ks], acc[m][n], 0, 0, 0);
        __builtin_amdgcn_s_setprio(0);
        if (pf) asm volatile("s_waitcnt vmcnt(4)" ::: "memory");
        else    asm volatile("s_waitcnt vmcnt(2)" ::: "memory");
        __builtin_amdgcn_s_barrier();

        // ---- phase 1: quadrant (0,1) ----
#pragma unroll
        for (int ks = 0; ks < 2; ++ks)
#pragma unroll
            for (int n = 0; n < 2; ++n) {
                int rho = wc * 32 + n * 16 + lr;
                b1[n][ks] = *(const h8*)&BS[cur][1][rho * 64 + ((ks * 4 + lq + rho) & 7) * 8];
            }
        if (pf) STAGE_B(nx, 0, kb);
        __builtin_amdgcn_s_barrier();
        __builtin_amdgcn_s_setprio(1);
#pragma unroll
        for (int ks = 0; ks < 2; ++ks)
#pragma unroll
            for (int m = 0; m < 4; ++m)
#pragma unroll
                for (int n = 0; n < 2; ++n)
                    acc[m][2 + n] = __builtin_amdgcn_mfma_f32_16x16x32_f16(
                        a0[m][ks], b1[n][ks], acc[m][2 + n], 0, 0, 0);
        __builtin_amdgcn_s_setprio(0);
        if (pf) asm volatile("s_waitcnt vmcnt(4)" ::: "memory");
        else    asm volatile("s_waitcnt vmcnt(0)" ::: "memory");
        __builtin_amdgcn_s_barrier();

        // ---- phase 2: quadrant (1,1) ----
#pragma unroll
        for (int ks = 0; ks < 2; ++ks)
#pragma unroll
            for (int m = 0; m < 4; ++m) {
                int rho = wr * 64 + m * 16 + lr;
                a1[m][ks] = *(const h8*)&AS[cur][1][rho * 64 + ((ks * 4 + lq + rho) & 7) * 8];
            }
        if (pf) STAGE_B(nx, 1, kb);
        __builtin_amdgcn_s_barrier();
        __builtin_amdgcn_s_setprio(1);
#pragma unroll
        for (int ks = 0; ks < 2; ++ks)
#pragma unroll
            for (int m = 0; m < 4; ++m)
#pragma unroll
                for (int n = 0; n < 2; ++n)
                    acc[4 + m][2 + n] = __builtin_amdgcn_mfma_f32_16x16x32_f16(
                        a1[m][ks], b1[n][ks], acc[4 + m][2 + n], 0, 0, 0);
        __builtin_amdgcn_s_setprio(0);
        __builtin_amdgcn_s_barrier();

        // ---- phase 3: quadrant (1,0) ----
#pragma unroll
        for (int ks = 0; ks < 2; ++ks)
#pragma unroll
            for (int n = 0; n < 2; ++n) {
                int rho = wc * 32 + n * 16 + lr;
                b0[n][ks] = *(const h8*)&BS[cur][0][rho * 64 + ((ks * 4 + lq + rho) & 7) * 8];
            }
        if (pf) STAGE_A(nx, 1, kb);
        __builtin_amdgcn_s_barrier();
        __builtin_amdgcn_s_setprio(1);
#pragma unroll
        for (int ks = 0; ks < 2; ++ks)
#pragma unroll
            for (int m = 0; m < 4; ++m)
#pragma unroll
                for (int n = 0; n < 2; ++n)
                    acc[4 + m][n] = __builtin_amdgcn_mfma_f32_16x16x32_f16(
                        a1[m][ks], b0[n][ks], acc[4 + m][n], 0, 0, 0);
        __builtin_amdgcn_s_setprio(0);
        if (pf) asm volatile("s_waitcnt vmcnt(4)" ::: "memory");
        __builtin_amdgcn_s_barrier();
        cur = nx;
    }
#undef STAGE_A
#undef STAGE_B

    const long row0 = (long)brow * 256 + wr * 128 + lq * 4;
    const long col0 = (long)col * 256 + wc * 64 + lr;

    if constexpr (MODE == 3) {
        _Float16* C = (_Float16*)Cout + (long)bz * sC;
#pragma unroll
        for (int i = 0; i < 8; ++i)
#pragma unroll
            for (int j = 0; j < 4; ++j)
#pragma unroll
                for (int r = 0; r < 4; ++r) {
                    float v = acc[i][j][r] * scale;
                    v = fminf(fmaxf(v, -60000.0f), 60000.0f);
                    C[(row0 + i * 16 + r) * (long)N + col0 + j * 16] = (_Float16)v;
                }
    } else {
        float bv[4];
        {
            const void* bp = bias; const int* bfp = biasFlag; long boff = 0;
            if (bias2 != nullptr && col * 256 >= (N >> 1)) {
                bp = bias2; bfp = biasFlag2; boff = (long)(N >> 1);
            }
            const int bIs = *bfp;
#pragma unroll
            for (int j = 0; j < 4; ++j) bv[j] = rd(bp, col0 + j * 16 - boff, bIs);
        }
        _Float16* C = (_Float16*)Cout + (long)bz * sC;
#pragma unroll
        for (int i = 0; i < 8; ++i)
#pragma unroll
            for (int j = 0; j < 4; ++j)
#pragma unroll
                for (int r = 0; r < 4; ++r) {
                    float v = acc[i][j][r] + bv[j];
                    v = fminf(fmaxf(v, -65000.0f), 65000.0f);
                    C[(row0 + i * 16 + r) * (long)N + col0 + j * 16] = (_Float16)v;
                }
    }
}

// ---------------------------------------------------------------------------
// Fused conv launch.
// Blocks [0,4096): dwconv q (0..2047) / k (2048..4095), 4 rows/block:
//   thread-group g=tid>>7 handles rows s, s+1 (s = sp*4 + 2g) via 4 row loads
//   x[s-1..s+2] -> 2 outputs (ILP + 33% fewer loads).
// Blocks [4096,6144): dwconv_v + transpose.
struct ConvP {
    const _Float16* x; int xs; _Float16* y;
    const _Float16* kp; const _Float16* cb; const float* tg;
};
__global__ void k_convs(ConvP p0, ConvP p1,
                        const _Float16* __restrict__ xv, int xvs,
                        _Float16* __restrict__ vt,
                        const _Float16* __restrict__ kpv,
                        const _Float16* __restrict__ cbv,
                        const float* __restrict__ tgv,
                        int S, int SK, int D) {
    __shared__ _Float16 T[64][65];
    const int bid = blockIdx.x, tid = threadIdx.x;
    h8 zero;
#pragma unroll
    for (int u = 0; u < 8; ++u) zero[u] = (_Float16)0.0f;

    if (bid < 4096) {
        const ConvP& p = (bid >= 2048) ? p1 : p0;
        int l = bid & 2047;
        int b = l >> 9, sp = l & 511;
        int g = tid >> 7;
        int s = sp * 4 + g * 2;
        int d0 = (tid & 127) * 8;
        const size_t rs = p.xs;
        const size_t xb = ((size_t)b * S + s) * rs + d0;
        h8 xA = (s > 0) ? *(const h8*)(p.x + xb - rs) : zero;
        h8 xB = *(const h8*)(p.x + xb);
        h8 xC = *(const h8*)(p.x + xb + rs);
        h8 xD = (s + 2 < S) ? *(const h8*)(p.x + xb + 2 * rs) : zero;
        h8 k0 = *(const h8*)(p.kp + 0 * D + d0);
        h8 k1 = *(const h8*)(p.kp + 1 * D + d0);
        h8 k2 = *(const h8*)(p.kp + 2 * D + d0);
        h8 cb = *(const h8*)(p.cb + d0);
        float tg = *p.tg;
        h8 o0, o1;
#pragma unroll
        for (int u = 0; u < 8; ++u) {
            float c0 = (float)xA[u] * (float)k0[u] + (float)xB[u] * (float)k1[u] +
                       (float)xC[u] * (float)k2[u] + (float)cb[u];
            float v0 = (float)xB[u] + tg * c0;
            o0[u] = (_Float16)fminf(fmaxf(v0, -65000.0f), 65000.0f);
            float c1 = (float)xB[u] * (float)k0[u] + (float)xC[u] * (float)k1[u] +
                       (float)xD[u] * (float)k2[u] + (float)cb[u];
            float v1 = (float)xC[u] + tg * c1;
            o1[u] = (_Float16)fminf(fmaxf(v1, -65000.0f), 65000.0f);
        }
        const size_t yb = ((size_t)b * S + s) * D + d0;
        *(h8*)(p.y + yb) = o0;
        *(h8*)(p.y + yb + D) = o1;
    } else {
        int l = bid - 4096;
        int bx = l & 31, by = (l >> 5) & 15, b = l >> 9;
        int s0 = bx * 64, d0 = by * 64;
        float tg = *tgv;
#pragma unroll
        for (int it = 0; it < 2; ++it) {
            int idx = it * 256 + tid;
            int r = idx >> 3, c = (idx & 7) * 8;
            int s = s0 + r;
            const size_t xb = ((size_t)b * SK + s) * xvs + d0 + c;
            h8 xc = *(const h8*)(xv + xb);
            h8 xp = (s > 0)      ? *(const h8*)(xv + xb - xvs) : zero;
            h8 xn = (s < SK - 1) ? *(const h8*)(xv + xb + xvs) : zero;
            h8 k0 = *(const h8*)(kpv + 0 * D + d0 + c);
            h8 k1 = *(const h8*)(kpv + 1 * D + d0 + c);
            h8 k2 = *(const h8*)(kpv + 2 * D + d0 + c);
            h8 cb = *(const h8*)(cbv + d0 + c);
#pragma unroll
            for (int u = 0; u < 8; ++u) {
                float cv = (float)xp[u] * (float)k0[u] + (float)xc[u] * (float)k1[u] +
                           (float)xn[u] * (float)k2[u] + (float)cb[u];
                float v = (float)xc[u] + tg * cv;
                T[r][c + u] = (_Float16)fminf(fmaxf(v, -65000.0f), 65000.0f);
            }
        }
        __syncthreads();
#pragma unroll
        for (int it = 0; it < 2; ++it) {
            int idx = it * 256 + tid;
            int dr = idx >> 3, c = (idx & 7) * 8;
            h8 o;
#pragma unroll
            for (int u = 0; u < 8; ++u) o[u] = T[c + u][dr];
            *(h8*)(vt + ((size_t)b * D + d0 + dr) * SK + s0 + c) = o;
        }
    }
}

// ---------------------------------------------------------------------------
// Row softmax + mask. Block bid = MASK row (0..2047); wave w = batch b.
// All 4 waves share mask row bid -> mask traffic /4 (L1/L2-hot for waves 1-3).
// Lane owns 4 interleaved h8 chunks (chunk c = j*64+lane, dense 16B/lane).
// Pure __shfl_xor 64-lane reduction: no LDS, no __syncthreads.
__global__ __launch_bounds__(256) void k_softmax(const _Float16* __restrict__ sc,
                                                 _Float16* __restrict__ pr,
                                                 const void* __restrict__ mraw,
                                                 const int* __restrict__ mwf,
                                                 int SK) {
    const int w = threadIdx.x >> 6;               // batch
    const long row = (long)w * 2048 + blockIdx.x; // scores row (b*SQ + r)
    const int lane = threadIdx.x & 63;
    const long rb = row * (long)SK;
    const long mrb = (long)blockIdx.x * SK;
    const int mw = *mwf;

    h8 v[4];
#pragma unroll
    for (int j = 0; j < 4; ++j)
        v[j] = *(const h8*)(sc + rb + (size_t)(j * 64 + lane) * 8);

    unsigned int km[4];
    if (mw == 4) {
#pragma unroll
        for (int j = 0; j < 4; ++j) {
            const unsigned int* mp = (const unsigned int*)mraw + mrb + (size_t)(j * 64 + lane) * 8;
            u32x4 m0 = *(const u32x4*)mp;
            u32x4 m1 = *(const u32x4*)(mp + 4);
            unsigned int k = 0;
#pragma unroll
            for (int u = 0; u < 4; ++u) {
                k |= (m0[u] != 0u) ? (1u << u) : 0u;
                k |= (m1[u] != 0u) ? (1u << (4 + u)) : 0u;
            }
            km[j] = k;
        }
    } else if (mw == 2) {
#pragma unroll
        for (int j = 0; j < 4; ++j) {
            us8 m8 = *(const us8*)((const unsigned short*)mraw + mrb + (size_t)(j * 64 + lane) * 8);
            unsigned int k = 0;
#pragma unroll
            for (int u = 0; u < 8; ++u) k |= (m8[u] != 0) ? (1u << u) : 0u;
            km[j] = k;
        }
    } else {
#pragma unroll
        for (int j = 0; j < 4; ++j) {
            unsigned long long m = *(const unsigned long long*)
                ((const unsigned char*)mraw + mrb + (size_t)(j * 64 + lane) * 8);
            unsigned int k = 0;
#pragma unroll
            for (int u = 0; u < 8; ++u) k |= ((m >> (8 * u)) & 0xFFull) ? (1u << u) : 0u;
            km[j] = k;
        }
    }

    float f[4][8];
    float mx = -3.0e38f;
#pragma unroll
    for (int j = 0; j < 4; ++j)
#pragma unroll
        for (int u = 0; u < 8; ++u) {
            f[j][u] = (km[j] & (1u << u)) ? (float)v[j][u] : -60000.0f;
            mx = fmaxf(mx, f[j][u]);
        }
#pragma unroll
    for (int o = 32; o > 0; o >>= 1) mx = fmaxf(mx, __shfl_xor(mx, o, 64));

    float sum = 0.0f;
#pragma unroll
    for (int j = 0; j < 4; ++j)
#pragma unroll
        for (int u = 0; u < 8; ++u) { f[j][u] = __expf(f[j][u] - mx); sum += f[j][u]; }
#pragma unroll
    for (int o = 32; o > 0; o >>= 1) sum += __shfl_xor(sum, o, 64);
    const float inv = 1.0f / sum;

#pragma unroll
    for (int j = 0; j < 4; ++j) {
        h8 o8;
#pragma unroll
        for (int u = 0; u < 8; ++u) o8[u] = (_Float16)(f[j][u] * inv);
        *(h8*)(pr + rb + (size_t)(j * 64 + lane) * 8) = o8;
    }
}

// ---------------------------------------------------------------------------
extern "C" void kernel_launch(void* const* d_in, const int* in_sizes, int n_in,
                              void* d_out, int out_size, void* d_ws, size_t ws_size,
                              hipStream_t stream) {
    const int Bn = 4, SQ = 2048, SK = 2048, D = 1024;
    const size_t nQ = (size_t)Bn * SQ * D;   // 8,388,608

    const void* qh = d_in[0];
    const void* mh = d_in[1];
    const void* mask = d_in[2];
    const void* q_w = d_in[3];
    const void* q_b = d_in[4];
    const void* k_w = d_in[5];
    const void* k_b = d_in[6];
    const void* v_w = d_in[7];
    const void* v_b = d_in[8];
    const void* o_w = d_in[9];
    const void* o_b = d_in[10];
    const void* q_kern = d_in[11];
    const void* q_cb   = d_in[12];
    const void* q_g    = d_in[13];
    const void* k_kern = d_in[14];
    const void* k_cb   = d_in[15];
    const void* k_g    = d_in[16];
    const void* v_kern = d_in[17];
    const void* v_cb   = d_in[18];
    const void* v_g    = d_in[19];

    // ---- workspace layout (lifetime-overlaid) ----
    // [0,33.5MB)        scores -> attn_out; par16/tgf live in the last 32KB
    //                   of this region from step 1 until k_convs (step 3),
    //                   clobbered only when scores is written (step 5)
    // [33.5,41.9MB)     w16 x4
    // [41.9,92.3MB)     lin_q + lin_kv; probs overlays after convs
    // [92.3,125.8MB)    qh16/mh16 staging -> conv_q, conv_k
    // [125.8,142.6MB)   vt  (must NOT alias lin_kv)
    // [142.6MB+)        flags
    char* ws = (char*)d_ws;
    _Float16* scores   = (_Float16*)(ws + 0);
    _Float16* attn_out = (_Float16*)(ws + 0);
    _Float16* par16    = (_Float16*)(ws + 33521664);          // 33.5MB - 32KB
    float*    tgf      = (float*)(ws + 33521664 + 24576);
    _Float16* w16      = (_Float16*)(ws + 33554432);
    _Float16* lin      = (_Float16*)(ws + 41943040);
    _Float16* lin_q    = lin;
    _Float16* lin_kv   = lin + nQ;
    _Float16* probs    = lin;
    _Float16* conv     = (_Float16*)(ws + 92274688);
    _Float16* qh16     = conv;
    _Float16* mh16     = conv + nQ;
    _Float16* vt       = (_Float16*)(ws + 125829120);
    int*      flags    = (int*)(ws + 142606336);

    // 1. fused probes + converts + conv params (8 launches total now)
    Ptr4 wp; wp.p[0] = q_w; wp.p[1] = k_w; wp.p[2] = v_w; wp.p[3] = o_w;
    Ptr4 bp; bp.p[0] = q_b; bp.p[1] = k_b; bp.p[2] = v_b; bp.p[3] = o_b;
    ConvSrc cs;
    cs.kern[0] = q_kern; cs.kern[1] = k_kern; cs.kern[2] = v_kern;
    cs.cb[0] = q_cb; cs.cb[1] = k_cb; cs.cb[2] = v_cb;
    cs.gate[0] = q_g; cs.gate[1] = k_g; cs.gate[2] = v_g;
    k_prep<<<2566, 256, 0, stream>>>(qh, mh, qh16, wp, w16, cs, par16, tgf,
                                     bp, (const unsigned int*)mask, flags);

    // 2. projections
    k_gemm_nt<1, 64><<<dim3(1024), 256, 0, stream>>>(
        qh16, w16, lin_q, q_b, flags + 9, nullptr, nullptr,
        D, D, 0, 0, 0, 8, 1);
    k_gemm16<1><<<dim3(256), 512, 0, stream>>>(
        mh16, w16 + (size_t)D * D, lin_kv, k_b, flags + 10, v_b, flags + 11,
        2 * D, D, 0, 0, 0, 1.0f, 8, 1);

    // 3. all three gated depthwise convs in one launch (2 rows/thread)
    ConvP cq{lin_q, D, conv + 0 * nQ, par16 + 0 * 3 * D, par16 + 9 * D + 0 * D, tgf + 0};
    ConvP ck{lin_kv, 2 * D, conv + 1 * nQ, par16 + 1 * 3 * D, par16 + 9 * D + 1 * D, tgf + 1};
    k_convs<<<dim3(6144), 256, 0, stream>>>(
        cq, ck, lin_kv + D, 2 * D, vt, par16 + 2 * 3 * D, par16 + 9 * D + 2 * D, tgf + 2,
        SQ, SK, D);

    // 5. scores: per-batch M=2048 (8 tiles), N=2048 (NT=8), BZ=4 -> 256 blocks
    k_gemm16<3><<<dim3(256), 512, 0, stream>>>(
        conv + 0 * nQ, conv + 1 * nQ, scores, nullptr, nullptr, nullptr, nullptr,
        SK, D, (long)SQ * D, (long)SK * D, (long)SQ * SK, 0.03125f, 8, 4);

    // 6. softmax + mask: block per mask row, 4 batch rows/block
    k_softmax<<<SQ, 256, 0, stream>>>(scores, probs, mask, flags + 16, SK);

    // 7. attn @ v: per-batch M=2048(64:32), N=1024 (NT=8), BZ=4 -> 1024 blocks
    k_gemm_nt<0, 64><<<dim3(1024), 256, 0, stream>>>(
        probs, vt, attn_out, nullptr, nullptr, nullptr, nullptr,
        D, SK, (long)SQ * SK, (long)D * SK, (long)SQ * D, 8, 4);

    // 8. out-proj: M=8192(64:128), N=1024 (NT=8), BZ=1 -> 1024 blocks, fp32 out
    k_gemm_nt<2, 64><<<dim3(1024), 256, 0, stream>>>(
        attn_out, w16 + 3 * (size_t)D * D, d_out, o_b, flags + 12, nullptr, nullptr,
        D, D, 0, 0, 0, 8, 1);

    (void)in_sizes; (void)n_in; (void)out_size; (void)ws_size;
}

// Round 11
// 375.155 us; speedup vs baseline: 1.0315x; 1.0198x over previous
//
#include <hip/hip_runtime.h>
#include <cstdint>
#include <cstddef>

// ---------------------------------------------------------------------------
// TransformConvCrossAttention: B=4, SQ=SK=2048, D=1024, Kconv=3
// fp16 compute, fp32 MFMA accumulation; fp32 in/out (runtime-verified).
// R21: R20 + MTILE=128 for the three k_gemm_nt GEMMs (q-proj, attn@V,
//      out-proj): 2x arithmetic intensity per staged byte (m97-ladder's
//      biggest step, 64->128 tile = 343->912 TF). Grids 1024->512 blocks
//      (2 blk/CU at 32KB LDS). The 128-variant template was verified in
//      this session (R10 ran <1,128>/<3,128> passing).
//      prep/convs/softmax/gemm16 byte-identical to R20.
// ---------------------------------------------------------------------------

#define GLOBAL_AS __attribute__((address_space(1)))
#define LDS_AS    __attribute__((address_space(3)))

typedef _Float16 h8 __attribute__((ext_vector_type(8)));
typedef _Float16 h4 __attribute__((ext_vector_type(4)));
typedef float    f4_t __attribute__((ext_vector_type(4)));
typedef unsigned short us8 __attribute__((ext_vector_type(8)));
typedef unsigned int u32x4 __attribute__((ext_vector_type(4)));

__device__ __forceinline__ float bf2f(unsigned short u) {
    union { unsigned int i; float f; } x; x.i = ((unsigned int)u) << 16; return x.f;
}
__device__ __forceinline__ float rd(const void* p, long i, int isBf) {
    return isBf ? bf2f(((const unsigned short*)p)[i]) : ((const float*)p)[i];
}
__device__ __forceinline__ int badHalf(unsigned int h) {
    int e = (int)((h >> 7) & 0xFF);
    return (e >= 0x8F || (e > 0 && e <= 0x60)) ? 1 : 0;
}

struct Ptr4 { const void* p[4]; };
struct ConvSrc { const void* kern[3]; const void* cb[3]; const void* gate[3]; };

// ---------------------------------------------------------------------------
// k_prep: fused dtype-probes + converts + conv params. Grid 2566 x 256 thr.
//   [0, 2048)   qh|mh -> fp16       [2048,2560) 4 weight mats
//   [2560]      conv params (self-sniffed)
//   [2561,2565) bias dtype probes -> flags[9..12]
//   [2565]      mask width probe  -> flags[16]
__global__ void k_prep(const void* __restrict__ qh, const void* __restrict__ mh,
                       _Float16* __restrict__ h16dst,
                       Ptr4 wsrc, _Float16* __restrict__ w16dst,
                       ConvSrc cs, _Float16* __restrict__ par16,
                       float* __restrict__ tgf,
                       Ptr4 bsrc, const unsigned int* __restrict__ mask,
                       int* __restrict__ flags) {
    __shared__ int s_cnt;
    __shared__ int vi32, vf32, vbf, vf16;
    const int bid = blockIdx.x, tid = threadIdx.x;

    if (bid < 2560) {
        const void* src;
        _Float16* dst;
        size_t gq, qmask, blk;
        if (bid < 2048) {
            const int seg = bid >> 10;
            src = seg ? mh : qh;
            blk = (size_t)bid;
            gq = blk * 2048 + tid;
            qmask = 2097151;
            dst = h16dst;
        } else {
            const int lb = bid - 2048;
            const int seg = lb >> 7;
            src = wsrc.p[seg];
            blk = (size_t)lb;
            gq = blk * 2048 + tid;
            qmask = 262143;
            dst = w16dst;
        }
        if (tid == 0) s_cnt = 0;
        __syncthreads();
        {
            size_t cidx = (blk * 1024 + tid) & (qmask >> 1);
            u32x4 w = *((const u32x4*)src + cidx);
            int bad = 0;
#pragma unroll
            for (int i = 0; i < 4; ++i) {
                bad += badHalf(w[i] & 0xFFFFu);
                bad += badHalf(w[i] >> 16);
            }
            if (bad) atomicAdd(&s_cnt, bad);
        }
        __syncthreads();
        const int isBf = !(s_cnt * 4 > 2048);

        if (isBf) {
            size_t cb = blk * 1024 + tid;
            size_t cmask = qmask >> 1;
            const unsigned short* sp = (const unsigned short*)src;
            us8 s[4];
#pragma unroll
            for (int k = 0; k < 4; ++k)
                s[k] = *(const us8*)(sp + ((cb + (size_t)k * 256) & cmask) * 8);
            asm volatile("" ::: "memory");
#pragma unroll
            for (int k = 0; k < 4; ++k) {
                h8 d;
#pragma unroll
                for (int u = 0; u < 8; ++u) d[u] = (_Float16)bf2f(s[k][u]);
                *(h8*)(dst + (cb + (size_t)k * 256) * 8) = d;
            }
        } else {
            const f4_t* fp = (const f4_t*)src;
            h4* dst4 = (h4*)dst;
            f4_t v[8];
#pragma unroll
            for (int k = 0; k < 8; ++k)
                v[k] = fp[(gq + (size_t)k * 256) & qmask];
            asm volatile("" ::: "memory");
#pragma unroll
            for (int k = 0; k < 8; ++k) {
                h4 d;
#pragma unroll
                for (int u = 0; u < 4; ++u) d[u] = (_Float16)v[k][u];
                dst4[gq + (size_t)k * 256] = d;
            }
        }
    } else if (bid == 2560) {
        const int D = 1024;
        int kIsv[3], cIsv[3];
#pragma unroll
        for (int t = 0; t < 3; ++t) {
            __syncthreads();
            if (tid == 0) s_cnt = 0;
            __syncthreads();
            {
                const unsigned short* ks = (const unsigned short*)cs.kern[t];
                int bad = 0;
#pragma unroll
                for (int i = 0; i < 8; ++i) bad += badHalf(ks[tid * 8 + i]);
                if (bad) atomicAdd(&s_cnt, bad);
            }
            __syncthreads();
            kIsv[t] = !(s_cnt * 4 > 2048);
            __syncthreads();
            if (tid == 0) s_cnt = 0;
            __syncthreads();
            {
                const unsigned short* bs = (const unsigned short*)cs.cb[t];
                int bad = 0;
#pragma unroll
                for (int i = 0; i < 4; ++i) bad += badHalf(bs[tid * 4 + i]);
                if (bad) atomicAdd(&s_cnt, bad);
            }
            __syncthreads();
            cIsv[t] = !(s_cnt * 4 > 1024);
        }
#pragma unroll
        for (int t = 0; t < 3; ++t) {
            for (int d = tid; d < D; d += 256) {
#pragma unroll
                for (int j = 0; j < 3; ++j)
                    par16[t * 3 * D + j * D + d] = (_Float16)rd(cs.kern[t], (long)d * 3 + j, kIsv[t]);
                par16[9 * D + t * D + d] = (_Float16)rd(cs.cb[t], d, cIsv[t]);
            }
        }
        if (tid < 3) {
            const void* g = cs.gate[tid];
            float gv = rd(g, 0, ((const unsigned int*)g)[0] == 0u ? 1 : 0);
            tgf[tid] = tanhf(gv);
        }
    } else if (bid < 2565) {
        const int idx = bid - 2561;
        const unsigned short* s = (const unsigned short*)bsrc.p[idx];
        if (tid == 0) s_cnt = 0;
        __syncthreads();
        int bad = 0;
        for (int i = tid; i < 1024; i += 256) bad += badHalf(s[i]);
        if (bad) atomicAdd(&s_cnt, bad);
        __syncthreads();
        if (tid == 0) flags[9 + idx] = (s_cnt * 4 > 1024) ? 0 : 1;
    } else {
        if (tid == 0) { vi32 = vf32 = vbf = vf16 = 0; }
        __syncthreads();
        int bi32 = 0, bf32 = 0, bbf = 0, bf16c = 0;
        for (int i = tid; i < 4096; i += 256) {
            unsigned int w = mask[i];
            if (!(w == 0u || w == 1u)) bi32++;
            if (!(w == 0u || w == 0x3F800000u)) bf32++;
            unsigned int h0 = w & 0xFFFFu, h1 = w >> 16;
            if (!((h0 == 0u || h0 == 0x3F80u) && (h1 == 0u || h1 == 0x3F80u))) bbf++;
            if (!((h0 == 0u || h0 == 0x3C00u) && (h1 == 0u || h1 == 0x3C00u))) bf16c++;
        }
        if (bi32) atomicAdd(&vi32, 1);
        if (bf32) atomicAdd(&vf32, 1);
        if (bbf)  atomicAdd(&vbf, 1);
        if (bf16c) atomicAdd(&vf16, 1);
        __syncthreads();
        if (tid == 0) {
            int w;
            if (vi32 == 0) w = 4;
            else if (vf32 == 0) w = 4;
            else if (vbf == 0) w = 2;
            else if (vf16 == 0) w = 2;
            else w = 1;
            flags[16] = w;
        }
    }
}

// ---------------------------------------------------------------------------
// R10 NT GEMM, MTILE x 128 x BK=64, 4 waves/block.
// MTILE=128: 32KB LDS -> 4 blocks/CU cap via __launch_bounds__(256,4)
// (2 blocks/CU at 160KB LDS budget). Verified in-session (R10: <1,128>,<3,128>).
// MODE 0: fp16 out  MODE 1: fp16 out + bias  MODE 2: fp32 out + bias
template <int MODE, int MTILE>
__global__ __launch_bounds__(256, 4) void k_gemm_nt(
    const _Float16* __restrict__ A, const _Float16* __restrict__ Bm,
    void* __restrict__ Cout,
    const void* __restrict__ bias, const int* __restrict__ biasFlag,
    const void* __restrict__ bias2, const int* __restrict__ biasFlag2,
    int N, int K, long sA, long sB, long sC,
    int NT, int BZ) {

    constexpr int NI = (MTILE == 128) ? 4 : 2;
    constexpr int NCA = MTILE / 32;
    __shared__ __align__(16) _Float16 As[MTILE * 64];
    __shared__ __align__(16) _Float16 Bs[128 * 64];

    const long id = blockIdx.x;
    const int xcd = (int)(id & 7);
    const long local = id >> 3;
    const int col = (int)(local % NT);
    const long g = (local / NT) * 8 + xcd;
    const int bz = (int)(g % BZ);
    const int brow = (int)(g / BZ);

    const int tid  = threadIdx.x;
    const int wave = tid >> 6, lane = tid & 63;
    const int wm = (wave >> 1) * (MTILE / 2), wn = (wave & 1) * 64;
    const int lr = lane & 15, lq = lane >> 4;

    const _Float16* Ab = A + (long)bz * sA + (size_t)brow * MTILE * K;
    const _Float16* Bb = Bm + (long)bz * sB + (size_t)col * 128 * K;

    f4_t acc[NI][4] = {};

    const _Float16* gA[NCA];
    _Float16* lA[NCA];
#pragma unroll
    for (int j = 0; j < NCA; ++j) {
        int c = tid + j * 256;
        int r = c >> 3, s = ((c & 7) - r) & 7;
        gA[j] = Ab + (size_t)r * K + s * 8;
        lA[j] = As + c * 8;
    }
    const _Float16* gB[4];
    _Float16* lB[4];
#pragma unroll
    for (int j = 0; j < 4; ++j) {
        int c = tid + j * 256;
        int r = c >> 3, s = ((c & 7) - r) & 7;
        gB[j] = Bb + (size_t)r * K + s * 8;
        lB[j] = Bs + c * 8;
    }

    for (int kb = 0; kb < K; kb += 64) {
#pragma unroll
        for (int j = 0; j < NCA; ++j)
            __builtin_amdgcn_global_load_lds((void GLOBAL_AS*)(gA[j] + kb), (void LDS_AS*)lA[j], 16, 0, 0);
#pragma unroll
        for (int j = 0; j < 4; ++j)
            __builtin_amdgcn_global_load_lds((void GLOBAL_AS*)(gB[j] + kb), (void LDS_AS*)lB[j], 16, 0, 0);
        __syncthreads();

#pragma unroll
        for (int t = 0; t < 2; ++t) {
            const int fs = ((t * 4 + lq + lr) & 7) * 8;
            h8 af[NI], bfr[4];
#pragma unroll
            for (int i = 0; i < NI; ++i) af[i]  = *(const h8*)&As[(wm + i * 16 + lr) * 64 + fs];
#pragma unroll
            for (int j = 0; j < 4; ++j) bfr[j] = *(const h8*)&Bs[(wn + j * 16 + lr) * 64 + fs];
#pragma unroll
            for (int i = 0; i < NI; ++i)
#pragma unroll
                for (int j = 0; j < 4; ++j)
                    acc[i][j] = __builtin_amdgcn_mfma_f32_16x16x32_f16(af[i], bfr[j], acc[i][j], 0, 0, 0);
        }
        __syncthreads();
    }

    const long row0 = (long)brow * MTILE + wm + lq * 4;
    const long col0 = (long)col * 128 + wn + lr;

    float bv[4];
    if constexpr (MODE != 0) {
        const void* bp = bias; const int* bfp = biasFlag; long boff = 0;
        if (bias2 != nullptr && col * 128 >= (N >> 1)) {
            bp = bias2; bfp = biasFlag2; boff = (long)(N >> 1);
        }
        const int bIs = *bfp;
#pragma unroll
        for (int j = 0; j < 4; ++j) bv[j] = rd(bp, col0 + j * 16 - boff, bIs);
    } else {
#pragma unroll
        for (int j = 0; j < 4; ++j) bv[j] = 0.0f;
    }
    if constexpr (MODE == 2) {
        float* C = (float*)Cout + (long)bz * sC;
#pragma unroll
        for (int i = 0; i < NI; ++i)
#pragma unroll
            for (int j = 0; j < 4; ++j)
#pragma unroll
                for (int r = 0; r < 4; ++r)
                    C[(row0 + i * 16 + r) * (long)N + col0 + j * 16] = acc[i][j][r] + bv[j];
    } else {
        _Float16* C = (_Float16*)Cout + (long)bz * sC;
#pragma unroll
        for (int i = 0; i < NI; ++i)
#pragma unroll
            for (int j = 0; j < 4; ++j)
#pragma unroll
                for (int r = 0; r < 4; ++r) {
                    float v = acc[i][j][r] + bv[j];
                    v = fminf(fmaxf(v, -65000.0f), 65000.0f);
                    C[(row0 + i * 16 + r) * (long)N + col0 + j * 16] = (_Float16)v;
                }
    }
}

// ---------------------------------------------------------------------------
// m201-family pipelined NT GEMM: 256 x 256 x BK=64, 512 thr = 8 waves (2Mx4N),
// wave out 128x64. 128KB LDS, 2 K-tile buffers, 4 phases/K-tile (C-quadrants
// of 16 MFMA), 2 global_load_lds per phase, counted vmcnt(4) at 3/4 phase
// closes (never 0 until final drain), setprio(1) around MFMA, seg-rotation
// swizzle (measured 0 conflicts). R13-verified loop.
// MODE 1: fp16 out + bias (bias2 = 2nd N-half)
// MODE 3: fp16 scores, scale+clamp only (mask applied later in softmax)
template <int MODE>
__global__ __launch_bounds__(512, 2) void k_gemm16(
    const _Float16* __restrict__ A, const _Float16* __restrict__ Bm,
    void* __restrict__ Cout,
    const void* __restrict__ bias, const int* __restrict__ biasFlag,
    const void* __restrict__ bias2, const int* __restrict__ biasFlag2,
    int N, int K, long sA, long sB, long sC,
    float scale, int NT, int BZ) {

    __shared__ __align__(16) _Float16 AS[2][2][8192];
    __shared__ __align__(16) _Float16 BS[2][2][8192];

    const long id = blockIdx.x;
    const int xcd = (int)(id & 7);
    const long local = id >> 3;
    const int col = (int)(local % NT);
    const long g = (local / NT) * 8 + xcd;
    const int bz = (int)(g % BZ);
    const int brow = (int)(g / BZ);

    const int tid  = threadIdx.x;
    const int wave = tid >> 6, lane = tid & 63;
    const int wr = wave >> 2, wc = wave & 3;
    const int lr = lane & 15, lq = lane >> 4;

    const _Float16* Ab = A + (long)bz * sA + (size_t)brow * 256 * K;
    const _Float16* Bb = Bm + (long)bz * sB + (size_t)col * 256 * K;

    f4_t acc[8][4] = {};

    const _Float16* gAsrc[2][2];
    const _Float16* gBsrc[2][2];
    int lOff[2];
#pragma unroll
    for (int j = 0; j < 2; ++j) {
        int c = tid + j * 512;
        int rho = c >> 3, s = ((c & 7) - rho) & 7;
        lOff[j] = c * 8;
#pragma unroll
        for (int gg = 0; gg < 2; ++gg) {
            int ra = gg * 64 + (rho & 63) + (rho >> 6) * 128;
            gAsrc[gg][j] = Ab + (size_t)ra * K + s * 8;
            int rb = gg * 32 + (rho & 31) + (rho >> 5) * 64;
            gBsrc[gg][j] = Bb + (size_t)rb * K + s * 8;
        }
    }

#define STAGE_A(buf, gg, kb)                                                              \
    do {                                                                                  \
        __builtin_amdgcn_global_load_lds((void GLOBAL_AS*)(gAsrc[gg][0] + (kb)),          \
                                         (void LDS_AS*)&AS[buf][gg][lOff[0]], 16, 0, 0);  \
        __builtin_amdgcn_global_load_lds((void GLOBAL_AS*)(gAsrc[gg][1] + (kb)),          \
                                         (void LDS_AS*)&AS[buf][gg][lOff[1]], 16, 0, 0);  \
    } while (0)
#define STAGE_B(buf, gg, kb)                                                              \
    do {                                                                                  \
        __builtin_amdgcn_global_load_lds((void GLOBAL_AS*)(gBsrc[gg][0] + (kb)),          \
                                         (void LDS_AS*)&BS[buf][gg][lOff[0]], 16, 0, 0);  \
        __builtin_amdgcn_global_load_lds((void GLOBAL_AS*)(gBsrc[gg][1] + (kb)),          \
                                         (void LDS_AS*)&BS[buf][gg][lOff[1]], 16, 0, 0);  \
    } while (0)

    const int nkt = K >> 6;

    STAGE_A(0, 0, 0);
    STAGE_B(0, 0, 0);
    STAGE_B(0, 1, 0);
    STAGE_A(0, 1, 0);
    asm volatile("s_waitcnt vmcnt(4)" ::: "memory");
    __builtin_amdgcn_s_barrier();

    int cur = 0;
    for (int t = 0; t < nkt; ++t) {
        const bool pf = (t + 1) < nkt;
        const long kb = (long)(t + 1) << 6;
        const int nx = cur ^ 1;
        h8 a0[4][2], a1[4][2], b0[2][2], b1[2][2];

        // ---- phase 0: quadrant (0,0) ----
#pragma unroll
        for (int ks = 0; ks < 2; ++ks) {
#pragma unroll
            for (int m = 0; m < 4; ++m) {
                int rho = wr * 64 + m * 16 + lr;
                a0[m][ks] = *(const h8*)&AS[cur][0][rho * 64 + ((ks * 4 + lq + rho) & 7) * 8];
            }
#pragma unroll
            for (int n = 0; n < 2; ++n) {
                int rho = wc * 32 + n * 16 + lr;
                b0[n][ks] = *(const h8*)&BS[cur][0][rho * 64 + ((ks * 4 + lq + rho) & 7) * 8];
            }
        }
        if (pf) STAGE_A(nx, 0, kb);
        __builtin_amdgcn_s_barrier();
        __builtin_amdgcn_s_setprio(1);
#pragma unroll
        for (int ks = 0; ks < 2; ++ks)
#pragma unroll
            for (int m = 0; m < 4; ++m)
#pragma unroll
                for (int n = 0; n < 2; ++n)
                    acc[m][n] = __builtin_amdgcn_mfma_f32_16x16x32_f16(
                        a0[m][ks], b0[n][ks], acc[m][n], 0, 0, 0);
        __builtin_amdgcn_s_setprio(0);
        if (pf) asm volatile("s_waitcnt vmcnt(4)" ::: "memory");
        else    asm volatile("s_waitcnt vmcnt(2)" ::: "memory");
        __builtin_amdgcn_s_barrier();

        // ---- phase 1: quadrant (0,1) ----
#pragma unroll
        for (int ks = 0; ks < 2; ++ks)
#pragma unroll
            for (int n = 0; n < 2; ++n) {
                int rho = wc * 32 + n * 16 + lr;
                b1[n][ks] = *(const h8*)&BS[cur][1][rho * 64 + ((ks * 4 + lq + rho) & 7) * 8];
            }
        if (pf) STAGE_B(nx, 0, kb);
        __builtin_amdgcn_s_barrier();
        __builtin_amdgcn_s_setprio(1);
#pragma unroll
        for (int ks = 0; ks < 2; ++ks)
#pragma unroll
            for (int m = 0; m < 4; ++m)
#pragma unroll
                for (int n = 0; n < 2; ++n)
                    acc[m][2 + n] = __builtin_amdgcn_mfma_f32_16x16x32_f16(
                        a0[m][ks], b1[n][ks], acc[m][2 + n], 0, 0, 0);
        __builtin_amdgcn_s_setprio(0);
        if (pf) asm volatile("s_waitcnt vmcnt(4)" ::: "memory");
        else    asm volatile("s_waitcnt vmcnt(0)" ::: "memory");
        __builtin_amdgcn_s_barrier();

        // ---- phase 2: quadrant (1,1) ----
#pragma unroll
        for (int ks = 0; ks < 2; ++ks)
#pragma unroll
            for (int m = 0; m < 4; ++m) {
                int rho = wr * 64 + m * 16 + lr;
                a1[m][ks] = *(const h8*)&AS[cur][1][rho * 64 + ((ks * 4 + lq + rho) & 7) * 8];
            }
        if (pf) STAGE_B(nx, 1, kb);
        __builtin_amdgcn_s_barrier();
        __builtin_amdgcn_s_setprio(1);
#pragma unroll
        for (int ks = 0; ks < 2; ++ks)
#pragma unroll
            for (int m = 0; m < 4; ++m)
#pragma unroll
                for (int n = 0; n < 2; ++n)
                    acc[4 + m][2 + n] = __builtin_amdgcn_mfma_f32_16x16x32_f16(
                        a1[m][ks], b1[n][ks], acc[4 + m][2 + n], 0, 0, 0);
        __builtin_amdgcn_s_setprio(0);
        __builtin_amdgcn_s_barrier();

        // ---- phase 3: quadrant (1,0) ----
#pragma unroll
        for (int ks = 0; ks < 2; ++ks)
#pragma unroll
            for (int n = 0; n < 2; ++n) {
                int rho = wc * 32 + n * 16 + lr;
                b0[n][ks] = *(const h8*)&BS[cur][0][rho * 64 + ((ks * 4 + lq + rho) & 7) * 8];
            }
        if (pf) STAGE_A(nx, 1, kb);
        __builtin_amdgcn_s_barrier();
        __builtin_amdgcn_s_setprio(1);
#pragma unroll
        for (int ks = 0; ks < 2; ++ks)
#pragma unroll
            for (int m = 0; m < 4; ++m)
#pragma unroll
                for (int n = 0; n < 2; ++n)
                    acc[4 + m][n] = __builtin_amdgcn_mfma_f32_16x16x32_f16(
                        a1[m][ks], b0[n][ks], acc[4 + m][n], 0, 0, 0);
        __builtin_amdgcn_s_setprio(0);
        if (pf) asm volatile("s_waitcnt vmcnt(4)" ::: "memory");
        __builtin_amdgcn_s_barrier();
        cur = nx;
    }
#undef STAGE_A
#undef STAGE_B

    const long row0 = (long)brow * 256 + wr * 128 + lq * 4;
    const long col0 = (long)col * 256 + wc * 64 + lr;

    if constexpr (MODE == 3) {
        _Float16* C = (_Float16*)Cout + (long)bz * sC;
#pragma unroll
        for (int i = 0; i < 8; ++i)
#pragma unroll
            for (int j = 0; j < 4; ++j)
#pragma unroll
                for (int r = 0; r < 4; ++r) {
                    float v = acc[i][j][r] * scale;
                    v = fminf(fmaxf(v, -60000.0f), 60000.0f);
                    C[(row0 + i * 16 + r) * (long)N + col0 + j * 16] = (_Float16)v;
                }
    } else {
        float bv[4];
        {
            const void* bp = bias; const int* bfp = biasFlag; long boff = 0;
            if (bias2 != nullptr && col * 256 >= (N >> 1)) {
                bp = bias2; bfp = biasFlag2; boff = (long)(N >> 1);
            }
            const int bIs = *bfp;
#pragma unroll
            for (int j = 0; j < 4; ++j) bv[j] = rd(bp, col0 + j * 16 - boff, bIs);
        }
        _Float16* C = (_Float16*)Cout + (long)bz * sC;
#pragma unroll
        for (int i = 0; i < 8; ++i)
#pragma unroll
            for (int j = 0; j < 4; ++j)
#pragma unroll
                for (int r = 0; r < 4; ++r) {
                    float v = acc[i][j][r] + bv[j];
                    v = fminf(fmaxf(v, -65000.0f), 65000.0f);
                    C[(row0 + i * 16 + r) * (long)N + col0 + j * 16] = (_Float16)v;
                }
    }
}

// ---------------------------------------------------------------------------
// Fused conv launch.
// Blocks [0,4096): dwconv q / k, 4 rows/block, 2 rows/thread.
// Blocks [4096,6144): dwconv_v + transpose.
struct ConvP {
    const _Float16* x; int xs; _Float16* y;
    const _Float16* kp; const _Float16* cb; const float* tg;
};
__global__ void k_convs(ConvP p0, ConvP p1,
                        const _Float16* __restrict__ xv, int xvs,
                        _Float16* __restrict__ vt,
                        const _Float16* __restrict__ kpv,
                        const _Float16* __restrict__ cbv,
                        const float* __restrict__ tgv,
                        int S, int SK, int D) {
    __shared__ _Float16 T[64][65];
    const int bid = blockIdx.x, tid = threadIdx.x;
    h8 zero;
#pragma unroll
    for (int u = 0; u < 8; ++u) zero[u] = (_Float16)0.0f;

    if (bid < 4096) {
        const ConvP& p = (bid >= 2048) ? p1 : p0;
        int l = bid & 2047;
        int b = l >> 9, sp = l & 511;
        int g = tid >> 7;
        int s = sp * 4 + g * 2;
        int d0 = (tid & 127) * 8;
        const size_t rs = p.xs;
        const size_t xb = ((size_t)b * S + s) * rs + d0;
        h8 xA = (s > 0) ? *(const h8*)(p.x + xb - rs) : zero;
        h8 xB = *(const h8*)(p.x + xb);
        h8 xC = *(const h8*)(p.x + xb + rs);
        h8 xD = (s + 2 < S) ? *(const h8*)(p.x + xb + 2 * rs) : zero;
        h8 k0 = *(const h8*)(p.kp + 0 * D + d0);
        h8 k1 = *(const h8*)(p.kp + 1 * D + d0);
        h8 k2 = *(const h8*)(p.kp + 2 * D + d0);
        h8 cb = *(const h8*)(p.cb + d0);
        float tg = *p.tg;
        h8 o0, o1;
#pragma unroll
        for (int u = 0; u < 8; ++u) {
            float c0 = (float)xA[u] * (float)k0[u] + (float)xB[u] * (float)k1[u] +
                       (float)xC[u] * (float)k2[u] + (float)cb[u];
            float v0 = (float)xB[u] + tg * c0;
            o0[u] = (_Float16)fminf(fmaxf(v0, -65000.0f), 65000.0f);
            float c1 = (float)xB[u] * (float)k0[u] + (float)xC[u] * (float)k1[u] +
                       (float)xD[u] * (float)k2[u] + (float)cb[u];
            float v1 = (float)xC[u] + tg * c1;
            o1[u] = (_Float16)fminf(fmaxf(v1, -65000.0f), 65000.0f);
        }
        const size_t yb = ((size_t)b * S + s) * D + d0;
        *(h8*)(p.y + yb) = o0;
        *(h8*)(p.y + yb + D) = o1;
    } else {
        int l = bid - 4096;
        int bx = l & 31, by = (l >> 5) & 15, b = l >> 9;
        int s0 = bx * 64, d0 = by * 64;
        float tg = *tgv;
#pragma unroll
        for (int it = 0; it < 2; ++it) {
            int idx = it * 256 + tid;
            int r = idx >> 3, c = (idx & 7) * 8;
            int s = s0 + r;
            const size_t xb = ((size_t)b * SK + s) * xvs + d0 + c;
            h8 xc = *(const h8*)(xv + xb);
            h8 xp = (s > 0)      ? *(const h8*)(xv + xb - xvs) : zero;
            h8 xn = (s < SK - 1) ? *(const h8*)(xv + xb + xvs) : zero;
            h8 k0 = *(const h8*)(kpv + 0 * D + d0 + c);
            h8 k1 = *(const h8*)(kpv + 1 * D + d0 + c);
            h8 k2 = *(const h8*)(kpv + 2 * D + d0 + c);
            h8 cb = *(const h8*)(cbv + d0 + c);
#pragma unroll
            for (int u = 0; u < 8; ++u) {
                float cv = (float)xp[u] * (float)k0[u] + (float)xc[u] * (float)k1[u] +
                           (float)xn[u] * (float)k2[u] + (float)cb[u];
                float v = (float)xc[u] + tg * cv;
                T[r][c + u] = (_Float16)fminf(fmaxf(v, -65000.0f), 65000.0f);
            }
        }
        __syncthreads();
#pragma unroll
        for (int it = 0; it < 2; ++it) {
            int idx = it * 256 + tid;
            int dr = idx >> 3, c = (idx & 7) * 8;
            h8 o;
#pragma unroll
            for (int u = 0; u < 8; ++u) o[u] = T[c + u][dr];
            *(h8*)(vt + ((size_t)b * D + d0 + dr) * SK + s0 + c) = o;
        }
    }
}

// ---------------------------------------------------------------------------
// Row softmax + mask. Block bid = MASK row (0..2047); wave w = batch b.
// All 4 waves share mask row bid -> mask traffic /4.
// Lane owns 4 interleaved h8 chunks; pure __shfl_xor 64-lane reduction.
__global__ __launch_bounds__(256) void k_softmax(const _Float16* __restrict__ sc,
                                                 _Float16* __restrict__ pr,
                                                 const void* __restrict__ mraw,
                                                 const int* __restrict__ mwf,
                                                 int SK) {
    const int w = threadIdx.x >> 6;
    const long row = (long)w * 2048 + blockIdx.x;
    const int lane = threadIdx.x & 63;
    const long rb = row * (long)SK;
    const long mrb = (long)blockIdx.x * SK;
    const int mw = *mwf;

    h8 v[4];
#pragma unroll
    for (int j = 0; j < 4; ++j)
        v[j] = *(const h8*)(sc + rb + (size_t)(j * 64 + lane) * 8);

    unsigned int km[4];
    if (mw == 4) {
#pragma unroll
        for (int j = 0; j < 4; ++j) {
            const unsigned int* mp = (const unsigned int*)mraw + mrb + (size_t)(j * 64 + lane) * 8;
            u32x4 m0 = *(const u32x4*)mp;
            u32x4 m1 = *(const u32x4*)(mp + 4);
            unsigned int k = 0;
#pragma unroll
            for (int u = 0; u < 4; ++u) {
                k |= (m0[u] != 0u) ? (1u << u) : 0u;
                k |= (m1[u] != 0u) ? (1u << (4 + u)) : 0u;
            }
            km[j] = k;
        }
    } else if (mw == 2) {
#pragma unroll
        for (int j = 0; j < 4; ++j) {
            us8 m8 = *(const us8*)((const unsigned short*)mraw + mrb + (size_t)(j * 64 + lane) * 8);
            unsigned int k = 0;
#pragma unroll
            for (int u = 0; u < 8; ++u) k |= (m8[u] != 0) ? (1u << u) : 0u;
            km[j] = k;
        }
    } else {
#pragma unroll
        for (int j = 0; j < 4; ++j) {
            unsigned long long m = *(const unsigned long long*)
                ((const unsigned char*)mraw + mrb + (size_t)(j * 64 + lane) * 8);
            unsigned int k = 0;
#pragma unroll
            for (int u = 0; u < 8; ++u) k |= ((m >> (8 * u)) & 0xFFull) ? (1u << u) : 0u;
            km[j] = k;
        }
    }

    float f[4][8];
    float mx = -3.0e38f;
#pragma unroll
    for (int j = 0; j < 4; ++j)
#pragma unroll
        for (int u = 0; u < 8; ++u) {
            f[j][u] = (km[j] & (1u << u)) ? (float)v[j][u] : -60000.0f;
            mx = fmaxf(mx, f[j][u]);
        }
#pragma unroll
    for (int o = 32; o > 0; o >>= 1) mx = fmaxf(mx, __shfl_xor(mx, o, 64));

    float sum = 0.0f;
#pragma unroll
    for (int j = 0; j < 4; ++j)
#pragma unroll
        for (int u = 0; u < 8; ++u) { f[j][u] = __expf(f[j][u] - mx); sum += f[j][u]; }
#pragma unroll
    for (int o = 32; o > 0; o >>= 1) sum += __shfl_xor(sum, o, 64);
    const float inv = 1.0f / sum;

#pragma unroll
    for (int j = 0; j < 4; ++j) {
        h8 o8;
#pragma unroll
        for (int u = 0; u < 8; ++u) o8[u] = (_Float16)(f[j][u] * inv);
        *(h8*)(pr + rb + (size_t)(j * 64 + lane) * 8) = o8;
    }
}

// ---------------------------------------------------------------------------
extern "C" void kernel_launch(void* const* d_in, const int* in_sizes, int n_in,
                              void* d_out, int out_size, void* d_ws, size_t ws_size,
                              hipStream_t stream) {
    const int Bn = 4, SQ = 2048, SK = 2048, D = 1024;
    const size_t nQ = (size_t)Bn * SQ * D;   // 8,388,608

    const void* qh = d_in[0];
    const void* mh = d_in[1];
    const void* mask = d_in[2];
    const void* q_w = d_in[3];
    const void* q_b = d_in[4];
    const void* k_w = d_in[5];
    const void* k_b = d_in[6];
    const void* v_w = d_in[7];
    const void* v_b = d_in[8];
    const void* o_w = d_in[9];
    const void* o_b = d_in[10];
    const void* q_kern = d_in[11];
    const void* q_cb   = d_in[12];
    const void* q_g    = d_in[13];
    const void* k_kern = d_in[14];
    const void* k_cb   = d_in[15];
    const void* k_g    = d_in[16];
    const void* v_kern = d_in[17];
    const void* v_cb   = d_in[18];
    const void* v_g    = d_in[19];

    // ---- workspace layout (lifetime-overlaid) ----
    char* ws = (char*)d_ws;
    _Float16* scores   = (_Float16*)(ws + 0);
    _Float16* attn_out = (_Float16*)(ws + 0);
    _Float16* par16    = (_Float16*)(ws + 33521664);          // 33.5MB - 32KB
    float*    tgf      = (float*)(ws + 33521664 + 24576);
    _Float16* w16      = (_Float16*)(ws + 33554432);
    _Float16* lin      = (_Float16*)(ws + 41943040);
    _Float16* lin_q    = lin;
    _Float16* lin_kv   = lin + nQ;
    _Float16* probs    = lin;
    _Float16* conv     = (_Float16*)(ws + 92274688);
    _Float16* qh16     = conv;
    _Float16* mh16     = conv + nQ;
    _Float16* vt       = (_Float16*)(ws + 125829120);
    int*      flags    = (int*)(ws + 142606336);

    // 1. fused probes + converts + conv params
    Ptr4 wp; wp.p[0] = q_w; wp.p[1] = k_w; wp.p[2] = v_w; wp.p[3] = o_w;
    Ptr4 bp; bp.p[0] = q_b; bp.p[1] = k_b; bp.p[2] = v_b; bp.p[3] = o_b;
    ConvSrc cs;
    cs.kern[0] = q_kern; cs.kern[1] = k_kern; cs.kern[2] = v_kern;
    cs.cb[0] = q_cb; cs.cb[1] = k_cb; cs.cb[2] = v_cb;
    cs.gate[0] = q_g; cs.gate[1] = k_g; cs.gate[2] = v_g;
    k_prep<<<2566, 256, 0, stream>>>(qh, mh, qh16, wp, w16, cs, par16, tgf,
                                     bp, (const unsigned int*)mask, flags);

    // 2. projections
    //    q-proj: MTILE=128, M=8192 (64 tiles) x N=1024 (NT=8) -> 512 blocks
    k_gemm_nt<1, 128><<<dim3(512), 256, 0, stream>>>(
        qh16, w16, lin_q, q_b, flags + 9, nullptr, nullptr,
        D, D, 0, 0, 0, 8, 1);
    k_gemm16<1><<<dim3(256), 512, 0, stream>>>(
        mh16, w16 + (size_t)D * D, lin_kv, k_b, flags + 10, v_b, flags + 11,
        2 * D, D, 0, 0, 0, 1.0f, 8, 1);

    // 3. all three gated depthwise convs in one launch
    ConvP cq{lin_q, D, conv + 0 * nQ, par16 + 0 * 3 * D, par16 + 9 * D + 0 * D, tgf + 0};
    ConvP ck{lin_kv, 2 * D, conv + 1 * nQ, par16 + 1 * 3 * D, par16 + 9 * D + 1 * D, tgf + 1};
    k_convs<<<dim3(6144), 256, 0, stream>>>(
        cq, ck, lin_kv + D, 2 * D, vt, par16 + 2 * 3 * D, par16 + 9 * D + 2 * D, tgf + 2,
        SQ, SK, D);

    // 5. scores: per-batch M=2048 (8 tiles), N=2048 (NT=8), BZ=4 -> 256 blocks
    k_gemm16<3><<<dim3(256), 512, 0, stream>>>(
        conv + 0 * nQ, conv + 1 * nQ, scores, nullptr, nullptr, nullptr, nullptr,
        SK, D, (long)SQ * D, (long)SK * D, (long)SQ * SK, 0.03125f, 8, 4);

    // 6. softmax + mask: block per mask row, 4 batch rows/block
    k_softmax<<<SQ, 256, 0, stream>>>(scores, probs, mask, flags + 16, SK);

    // 7. attn @ v: MTILE=128, per-batch M=2048 (16 tiles), N=1024 (NT=8),
    //    BZ=4 -> 512 blocks
    k_gemm_nt<0, 128><<<dim3(512), 256, 0, stream>>>(
        probs, vt, attn_out, nullptr, nullptr, nullptr, nullptr,
        D, SK, (long)SQ * SK, (long)D * SK, (long)SQ * D, 8, 4);

    // 8. out-proj: MTILE=128, M=8192 (64 tiles), N=1024 (NT=8), BZ=1
    //    -> 512 blocks, fp32 out
    k_gemm_nt<2, 128><<<dim3(512), 256, 0, stream>>>(
        attn_out, w16 + 3 * (size_t)D * D, d_out, o_b, flags + 12, nullptr, nullptr,
        D, D, 0, 0, 0, 8, 1);

    (void)in_sizes; (void)n_in; (void)out_size; (void)ws_size;
}